// Round 1
// baseline (992.908 us; speedup 1.0000x reference)
//
#include <hip/hip_runtime.h>
#include <hip/hip_bf16.h>
#include <math.h>

typedef __hip_bfloat16 bf16;
typedef __attribute__((ext_vector_type(8))) short short8;
typedef __attribute__((ext_vector_type(4))) float floatx4;

#define SEQ    2048
#define TTOK   4096
#define DM     1024
#define NHEAD  16
#define NKVH   4
#define HD     64
#define NEXP   8
#define HIDDEN 1365
#define HIDP   1408
#define CAPT   1280
#define NSLOT  (NEXP*CAPT)   /* 10240 */

// ---------------------------------------------------------------- utilities
__device__ __forceinline__ void gld16(const void* g, void* l) {
  // async global->LDS, 16B per lane; LDS dest = wave-uniform base + lane*16
  __builtin_amdgcn_global_load_lds((const __attribute__((address_space(1))) void*)g,
                                   (__attribute__((address_space(3))) void*)l,
                                   16, 0, 0);
}

struct __align__(8) bf4 { bf16 x, y, z, w; };

// ---------------------------------------------------- weight convert+transpose
// src: (K,N) f32 row-major -> dst: (N,Kp) bf16 row-major, zero-fill k in [K,Kp)
__global__ __launch_bounds__(256) void transpose_cvt(
    const float* __restrict__ src, bf16* __restrict__ dst,
    int K, int N, int Kp, long srcZ, long dstZ) {
  src += (size_t)blockIdx.z * srcZ;
  dst += (size_t)blockIdx.z * dstZ;
  __shared__ float tile[32][33];
  int tid = threadIdx.x;
  int tx = tid & 31, ty = tid >> 5;            // 32 x 8
  int k0 = blockIdx.y * 32, n0 = blockIdx.x * 32;
#pragma unroll
  for (int i = 0; i < 4; ++i) {
    int k = k0 + ty + i * 8, n = n0 + tx;
    tile[ty + i * 8][tx] = (k < K && n < N) ? src[(size_t)k * N + n] : 0.f;
  }
  __syncthreads();
#pragma unroll
  for (int i = 0; i < 4; ++i) {
    int n = n0 + ty + i * 8, k = k0 + tx;
    if (n < N && k < Kp) dst[(size_t)n * Kp + k] = (bf16)tile[tx][ty + i * 8];
  }
}

// ---------------------------------------------------------------- rmsnorm
__global__ __launch_bounds__(256) void rmsnorm_kernel(
    const float* __restrict__ x, const float* __restrict__ w, bf16* __restrict__ out) {
  int t = blockIdx.x;
  const float* xr = x + (size_t)t * DM;
  float4 xv = *(const float4*)(xr + threadIdx.x * 4);
  float ss = xv.x * xv.x + xv.y * xv.y + xv.z * xv.z + xv.w * xv.w;
#pragma unroll
  for (int off = 1; off < 64; off <<= 1) ss += __shfl_xor(ss, off);
  __shared__ float sred[4];
  if ((threadIdx.x & 63) == 0) sred[threadIdx.x >> 6] = ss;
  __syncthreads();
  float scale = rsqrtf((sred[0] + sred[1] + sred[2] + sred[3]) * (1.f / DM) + 1e-6f);
  float4 wv = *(const float4*)(w + threadIdx.x * 4);
  bf4 o;
  o.x = (bf16)(xv.x * scale * wv.x); o.y = (bf16)(xv.y * scale * wv.y);
  o.z = (bf16)(xv.z * scale * wv.z); o.w = (bf16)(xv.w * scale * wv.w);
  ((bf4*)(out + (size_t)t * DM))[threadIdx.x] = o;
}

// ---------------------------------------------------------------- GEMM
// C(MxN) = A(MxK) @ Bt(NxK)^T ; 128x128 tile, BK=64, 4 waves, 16x16x32 bf16 MFMA
// EPI: 0 = Cf f32 store ; 1 = Cb bf16 store ; 2 = Cf = resid + acc ;
//      3 = atomicAdd(scatOut[tok[row]*ldc+col], gateW[row]*acc)
template <int EPI, bool GATHER, bool MOE>
__global__ __launch_bounds__(256) void gemm_bt(
    const bf16* __restrict__ A, const bf16* __restrict__ Bt,
    int M, int N, int K, int lda, int ldb, long bStrideE,
    float* __restrict__ Cf, bf16* __restrict__ Cb, int ldc,
    const float* __restrict__ resid,
    const int* __restrict__ tokList, const int* __restrict__ neCnt,
    const float* __restrict__ gateW, float* __restrict__ scatOut) {
  __shared__ __align__(16) bf16 As[128 * 64];
  __shared__ __align__(16) bf16 Bs[128 * 64];
  const int tid = threadIdx.x, lane = tid & 63, wave = tid >> 6;
  int m0, expert = 0, mLimit;
  if constexpr (MOE) {
    int slot0 = blockIdx.x * 128;
    expert = slot0 / CAPT;
    int local0 = slot0 - expert * CAPT;
    int ne = neCnt[expert];
    if (local0 >= ne) return;
    m0 = slot0;
    mLimit = ne - local0;
  } else {
    m0 = blockIdx.x * 128;
    mLimit = M - m0;
  }
  if (mLimit > 128) mLimit = 128;
  const int n0 = blockIdx.y * 128;
  const bf16* Bte = Bt + (MOE ? (long)expert * bStrideE : 0L);

  // staging sources: chunk c = it*256+tid covers (r = c/8, pos q = c%8),
  // holding data k-chunk kq = q ^ (r&7)  (xor swizzle; 2-way bank alias max)
  const bf16* aSrc[4]; const bf16* bSrc[4];
  bf16* aDst[4]; bf16* bDst[4];
#pragma unroll
  for (int it = 0; it < 4; ++it) {
    int c = it * 256 + tid;
    int r = c >> 3, q = c & 7;
    int kq = q ^ (r & 7);
    int rr = r < mLimit ? r : (mLimit - 1);
    long arow;
    if constexpr (GATHER) arow = tokList[m0 + rr];
    else arow = (long)(m0 + rr);
    aSrc[it] = A + arow * lda + kq * 8;
    int nn = n0 + r; if (nn > N - 1) nn = N - 1;
    bSrc[it] = Bte + (long)nn * ldb + kq * 8;
    bf16* dbase_a = As + (size_t)(it * 256 + wave * 64) * 8; // wave-uniform
    bf16* dbase_b = Bs + (size_t)(it * 256 + wave * 64) * 8;
    aDst[it] = dbase_a; bDst[it] = dbase_b;
  }

  floatx4 acc[4][4];
#pragma unroll
  for (int i = 0; i < 4; ++i)
#pragma unroll
    for (int j = 0; j < 4; ++j) { floatx4 z = {0.f, 0.f, 0.f, 0.f}; acc[i][j] = z; }

  const int wm = (wave & 1) * 64, wn = (wave >> 1) * 64;
  const int l15 = lane & 15, quad = lane >> 4;
  int aOff[4][2], bOff[4][2];
#pragma unroll
  for (int i = 0; i < 4; ++i) {
    int m = wm + i * 16 + l15;
    int n = wn + i * 16 + l15;
#pragma unroll
    for (int h = 0; h < 2; ++h) {
      aOff[i][h] = (((m << 3) | ((h * 4 + quad) ^ (m & 7))) << 3);
      bOff[i][h] = (((n << 3) | ((h * 4 + quad) ^ (n & 7))) << 3);
    }
  }

  const int kIters = K >> 6;
  for (int kt = 0; kt < kIters; ++kt) {
    __syncthreads();
#pragma unroll
    for (int it = 0; it < 4; ++it) {
      gld16(aSrc[it], aDst[it]);
      gld16(bSrc[it], bDst[it]);
      aSrc[it] += 64; bSrc[it] += 64;
    }
    __syncthreads();   // compiler emits vmcnt(0) drain before s_barrier
#pragma unroll
    for (int h = 0; h < 2; ++h) {
      short8 af[4], bfr[4];
#pragma unroll
      for (int i = 0; i < 4; ++i) af[i] = *(const short8*)(As + aOff[i][h]);
#pragma unroll
      for (int j = 0; j < 4; ++j) bfr[j] = *(const short8*)(Bs + bOff[j][h]);
#pragma unroll
      for (int i = 0; i < 4; ++i)
#pragma unroll
        for (int j = 0; j < 4; ++j)
          acc[i][j] = __builtin_amdgcn_mfma_f32_16x16x32_bf16(af[i], bfr[j], acc[i][j], 0, 0, 0);
    }
  }

  // epilogue: C row = quad*4+reg, col = lane&15 (m89-verified layout)
#pragma unroll
  for (int i = 0; i < 4; ++i) {
#pragma unroll
    for (int j = 0; j < 4; ++j) {
      int col = n0 + wn + j * 16 + l15;
#pragma unroll
      for (int r = 0; r < 4; ++r) {
        int row = wm + i * 16 + quad * 4 + r;
        if (row >= mLimit || col >= N) continue;
        float v = acc[i][j][r];
        if constexpr (EPI == 0) {
          Cf[(size_t)(m0 + row) * ldc + col] = v;
        } else if constexpr (EPI == 1) {
          Cb[(size_t)(m0 + row) * ldc + col] = (bf16)v;
        } else if constexpr (EPI == 2) {
          size_t o = (size_t)(m0 + row) * ldc + col;
          Cf[o] = resid[o] + v;
        } else {
          int tok = tokList[m0 + row];
          atomicAdd(&scatOut[(size_t)tok * ldc + col], gateW[m0 + row] * v);
        }
      }
    }
  }
}

// ---------------------------------------------------------------- RoPE + outputs
__global__ __launch_bounds__(256) void rope_kernel(
    const float* __restrict__ qkv, const float* __restrict__ cosb, const float* __restrict__ sinb,
    bf16* __restrict__ qb, bf16* __restrict__ kb, bf16* __restrict__ vb,
    float* __restrict__ newk, float* __restrict__ newv) {
  int t = blockIdx.x, s = t & (SEQ - 1);
  const float* base = qkv + (size_t)t * 1536;
  int tid = threadIdx.x;
  for (int p = tid; p < 512; p += 256) {        // Q: 16 heads x 32 pairs
    int hd = p >> 5, d = p & 31;
    float x1 = base[hd * 64 + d], x2 = base[hd * 64 + d + 32];
    float c = cosb[s * 64 + d], sn = sinb[s * 64 + d];
    qb[(size_t)t * DM + hd * 64 + d]      = (bf16)(x1 * c - x2 * sn);
    qb[(size_t)t * DM + hd * 64 + d + 32] = (bf16)(x1 * sn + x2 * c);
  }
  for (int p = tid; p < 128; p += 256) {        // K: 4 heads x 32 pairs
    int hd = p >> 5, d = p & 31;
    float x1 = base[1024 + hd * 64 + d], x2 = base[1024 + hd * 64 + d + 32];
    float c = cosb[s * 64 + d], sn = sinb[s * 64 + d];
    float o1 = x1 * c - x2 * sn, o2 = x1 * sn + x2 * c;
    kb[(size_t)t * 256 + hd * 64 + d]      = (bf16)o1;
    kb[(size_t)t * 256 + hd * 64 + d + 32] = (bf16)o2;
    newk[(size_t)t * 256 + hd * 64 + d]      = o1;
    newk[(size_t)t * 256 + hd * 64 + d + 32] = o2;
  }
  {                                             // V copy
    float xv = base[1280 + tid];
    vb[(size_t)t * 256 + tid] = (bf16)xv;
    newv[(size_t)t * 256 + tid] = xv;
  }
}

// ---------------------------------------------------------------- flash attention
#define APAD 72   /* 64 + 8 bf16: 144B row stride -> 2-way bank alias max */
__global__ __launch_bounds__(256) void attn_kernel(
    const bf16* __restrict__ Q, const bf16* __restrict__ Kc, const bf16* __restrict__ Vc,
    bf16* __restrict__ AO) {
  __shared__ __align__(16) bf16 Qs[64 * APAD];
  __shared__ __align__(16) bf16 Ks[64 * APAD];
  __shared__ __align__(16) bf16 Vts[64 * APAD];
  __shared__ __align__(16) bf16 Ps[4][16 * APAD];
  int q0 = blockIdx.x * 64, h = blockIdx.y, b = blockIdx.z;
  int g = h >> 2;
  int tid = threadIdx.x, lane = tid & 63, wave = tid >> 6;
  int l15 = lane & 15, quad = lane >> 4;

  for (int c = tid; c < 512; c += 256) {
    int r = c >> 3, d8 = (c & 7) * 8;
    const bf16* src = Q + ((size_t)(b * SEQ + q0 + r) * DM + h * 64 + d8);
    *(short8*)(Qs + r * APAD + d8) = *(const short8*)src;
  }

  float m_i[4], l_i[4];
  floatx4 oacc[4];
#pragma unroll
  for (int r = 0; r < 4; ++r) { m_i[r] = -1e30f; l_i[r] = 0.f; floatx4 z = {0.f,0.f,0.f,0.f}; oacc[r] = z; }

  int nkt = (q0 >> 6) + 1;
  for (int kt = 0; kt < nkt; ++kt) {
    __syncthreads();
    for (int c = tid; c < 512; c += 256) {
      int r = c >> 3, d8 = (c & 7) * 8;
      const bf16* ksrc = Kc + ((size_t)(b * SEQ + kt * 64 + r) * 256 + g * 64 + d8);
      *(short8*)(Ks + r * APAD + d8) = *(const short8*)ksrc;
      const bf16* vsrc = Vc + ((size_t)(b * SEQ + kt * 64 + r) * 256 + g * 64 + d8);
      short8 vv = *(const short8*)vsrc;
#pragma unroll
      for (int x2 = 0; x2 < 8; ++x2) Vts[(d8 + x2) * APAD + r] = ((const bf16*)&vv)[x2];
    }
    __syncthreads();

    floatx4 sacc[4];
#pragma unroll
    for (int j = 0; j < 4; ++j) { floatx4 z = {0.f,0.f,0.f,0.f}; sacc[j] = z; }
#pragma unroll
    for (int hh = 0; hh < 2; ++hh) {
      short8 aq = *(const short8*)(Qs + (wave * 16 + l15) * APAD + (hh * 4 + quad) * 8);
#pragma unroll
      for (int j = 0; j < 4; ++j) {
        short8 bk = *(const short8*)(Ks + (j * 16 + l15) * APAD + (hh * 4 + quad) * 8);
        sacc[j] = __builtin_amdgcn_mfma_f32_16x16x32_bf16(aq, bk, sacc[j], 0, 0, 0);
      }
    }
    int qrow_base = q0 + wave * 16 + quad * 4;
    float mnew[4];
#pragma unroll
    for (int r = 0; r < 4; ++r) mnew[r] = m_i[r];
#pragma unroll
    for (int j = 0; j < 4; ++j) {
      int colg = kt * 64 + j * 16 + l15;
#pragma unroll
      for (int r = 0; r < 4; ++r) {
        float sv = sacc[j][r] * 0.125f;
        if (colg > qrow_base + r) sv = -1e30f;
        sacc[j][r] = sv;
        mnew[r] = fmaxf(mnew[r], sv);
      }
    }
#pragma unroll
    for (int r = 0; r < 4; ++r)
#pragma unroll
      for (int off = 1; off < 16; off <<= 1) mnew[r] = fmaxf(mnew[r], __shfl_xor(mnew[r], off));
    float alpha[4], psum[4];
#pragma unroll
    for (int r = 0; r < 4; ++r) { alpha[r] = expf(m_i[r] - mnew[r]); m_i[r] = mnew[r]; psum[r] = 0.f; }
#pragma unroll
    for (int j = 0; j < 4; ++j)
#pragma unroll
      for (int r = 0; r < 4; ++r) {
        float p = expf(sacc[j][r] - m_i[r]);
        psum[r] += p;
        Ps[wave][(quad * 4 + r) * APAD + j * 16 + l15] = (bf16)p;
      }
#pragma unroll
    for (int r = 0; r < 4; ++r) {
#pragma unroll
      for (int off = 1; off < 16; off <<= 1) psum[r] += __shfl_xor(psum[r], off);
      l_i[r] = l_i[r] * alpha[r] + psum[r];
    }
#pragma unroll
    for (int j = 0; j < 4; ++j)
#pragma unroll
      for (int r = 0; r < 4; ++r) oacc[j][r] *= alpha[r];
    asm volatile("s_waitcnt lgkmcnt(0)" ::: "memory");
#pragma unroll
    for (int hh = 0; hh < 2; ++hh) {
      short8 ap = *(const short8*)(&Ps[wave][l15 * APAD + (hh * 4 + quad) * 8]);
#pragma unroll
      for (int j = 0; j < 4; ++j) {
        short8 bv = *(const short8*)(Vts + (j * 16 + l15) * APAD + (hh * 4 + quad) * 8);
        oacc[j] = __builtin_amdgcn_mfma_f32_16x16x32_bf16(ap, bv, oacc[j], 0, 0, 0);
      }
    }
  }
#pragma unroll
  for (int j = 0; j < 4; ++j)
#pragma unroll
    for (int r = 0; r < 4; ++r) {
      int t = b * SEQ + q0 + wave * 16 + quad * 4 + r;
      AO[(size_t)t * DM + h * 64 + j * 16 + l15] = (bf16)(oacc[j][r] / l_i[r]);
    }
}

// ---------------------------------------------------------------- router
__global__ __launch_bounds__(64) void router_kernel(
    const bf16* __restrict__ hn, const float* __restrict__ rw,
    float* __restrict__ probs, int* __restrict__ tIdx, float* __restrict__ tW) {
  int t = blockIdx.x, lane = threadIdx.x;
  float acc[8] = {0, 0, 0, 0, 0, 0, 0, 0};
  for (int d = lane; d < DM; d += 64) {
    float xv = (float)hn[(size_t)t * DM + d];
#pragma unroll
    for (int e = 0; e < 8; ++e) acc[e] += xv * rw[d * 8 + e];
  }
#pragma unroll
  for (int e = 0; e < 8; ++e)
#pragma unroll
    for (int off = 1; off < 64; off <<= 1) acc[e] += __shfl_xor(acc[e], off);
  if (lane == 0) {
    float mx = acc[0];
#pragma unroll
    for (int e = 1; e < 8; ++e) mx = fmaxf(mx, acc[e]);
    float p[8], se = 0.f;
#pragma unroll
    for (int e = 0; e < 8; ++e) { p[e] = expf(acc[e] - mx); se += p[e]; }
#pragma unroll
    for (int e = 0; e < 8; ++e) { p[e] /= se; probs[t * 8 + e] = p[e]; }
    int i1 = 0;
#pragma unroll
    for (int e = 1; e < 8; ++e) if (p[e] > p[i1]) i1 = e;
    int i2 = (i1 == 0) ? 1 : 0;
#pragma unroll
    for (int e = 0; e < 8; ++e) if (e != i1 && p[e] > p[i2]) i2 = e;
    float s = p[i1] + p[i2];
    tIdx[t * 2] = i1; tIdx[t * 2 + 1] = i2;
    tW[t * 2] = p[i1] / s; tW[t * 2 + 1] = p[i2] / s;
  }
}

// ------------------------------------------------- capacity assignment + aux
__global__ __launch_bounds__(256) void assign_kernel(
    const float* __restrict__ probs, const int* __restrict__ tIdx, const float* __restrict__ tW,
    int* __restrict__ tokList, float* __restrict__ gateW, int* __restrict__ neCnt,
    float* __restrict__ outAux) {
  __shared__ float psum[8];
  __shared__ int cnt[8];
  __shared__ int waveTot[4];
  __shared__ int offs;
  int tid = threadIdx.x, lane = tid & 63, wv = tid >> 6;
  if (tid < 8) { psum[tid] = 0.f; cnt[tid] = 0; }
  __syncthreads();
  float lp[8] = {0, 0, 0, 0, 0, 0, 0, 0};
  int lc[8] = {0, 0, 0, 0, 0, 0, 0, 0};
  for (int t = tid; t < TTOK; t += 256) {
    int a = tIdx[t * 2], b2 = tIdx[t * 2 + 1];
#pragma unroll
    for (int e = 0; e < 8; ++e) {
      lc[e] += (a == e) + (b2 == e);
      lp[e] += probs[t * 8 + e];
    }
  }
#pragma unroll
  for (int e = 0; e < 8; ++e) { atomicAdd(&psum[e], lp[e]); atomicAdd(&cnt[e], lc[e]); }
  __syncthreads();
  if (tid == 0) {
    float aux = 0.f; int used = 0;
    for (int e = 0; e < 8; ++e) {
      aux += (psum[e] / (float)TTOK) * ((float)cnt[e] / (float)TTOK);
      if (cnt[e] > 0) used++;
    }
    outAux[0] = 8.f * aux;
    outAux[1] = 100.f * (float)used / 8.f;
  }
  for (int e = 0; e < 8; ++e) {
    if (tid == 0) offs = 0;
    __syncthreads();
    for (int base = 0; base < TTOK; base += 256) {
      int t = base + tid;
      int a = tIdx[t * 2], b2 = tIdx[t * 2 + 1];
      bool sel = (a == e) || (b2 == e);
      unsigned long long mask = __ballot(sel);
      int wrank = __popcll(mask & ((1ull << lane) - 1ull));
      if (lane == 0) waveTot[wv] = __popcll(mask);
      __syncthreads();
      int pre = offs;
      for (int w2 = 0; w2 < wv; ++w2) pre += waveTot[w2];
      int rank = pre + wrank;
      if (sel && rank < CAPT) {
        tokList[e * CAPT + rank] = t;
        gateW[e * CAPT + rank] = (a == e) ? tW[t * 2] : tW[t * 2 + 1];
      }
      __syncthreads();
      if (tid == 0) offs += waveTot[0] + waveTot[1] + waveTot[2] + waveTot[3];
      __syncthreads();
    }
    if (tid == 0) neCnt[e] = offs < CAPT ? offs : CAPT;
    __syncthreads();
  }
}

// ---------------------------------------------------------------- silu * mul
__global__ __launch_bounds__(256) void act_kernel(
    const bf16* __restrict__ h1, const bf16* __restrict__ h3, bf16* __restrict__ act, int rows) {
  int idx = blockIdx.x * 256 + threadIdx.x;
  int total = rows * HIDP;
  if (idx >= total) return;
  int row = idx / HIDP, col = idx - row * HIDP;
  float v = 0.f;
  if (col < HIDDEN) {
    float a = (float)h1[(size_t)row * HIDDEN + col];
    float b = (float)h3[(size_t)row * HIDDEN + col];
    v = a / (1.f + expf(-a)) * b;
  }
  act[idx] = (bf16)v;
}

// ---------------------------------------------------------------- launch
extern "C" void kernel_launch(void* const* d_in, const int* in_sizes, int n_in,
                              void* d_out, int out_size, void* d_ws, size_t ws_size,
                              hipStream_t stream) {
  (void)in_sizes; (void)n_in; (void)out_size; (void)ws_size;
  const float* x     = (const float*)d_in[0];
  const float* cosb  = (const float*)d_in[1];
  const float* sinb  = (const float*)d_in[2];
  const float* attnw = (const float*)d_in[4];
  const float* moew  = (const float*)d_in[5];
  const float* wq  = (const float*)d_in[6];
  const float* wk  = (const float*)d_in[7];
  const float* wv  = (const float*)d_in[8];
  const float* wo  = (const float*)d_in[9];
  const float* rw  = (const float*)d_in[10];
  const float* ew1 = (const float*)d_in[11];
  const float* ew2 = (const float*)d_in[12];
  const float* ew3 = (const float*)d_in[13];
  const float* sw1 = (const float*)d_in[14];
  const float* sw2 = (const float*)d_in[15];
  const float* sw3 = (const float*)d_in[16];

  float* outp = (float*)d_out;
  float* auxp = outp + 4194304;
  float* newk = outp + 4194306;
  float* newv = newk + 1048576;

  char* wsp = (char*)d_ws;
  size_t off = 0;
  auto alloc = [&](size_t bytes) -> void* {
    void* p = wsp + off; off += (bytes + 255) & ~(size_t)255; return p;
  };
  bf16* wqkvT = (bf16*)alloc((size_t)1536 * 1024 * 2);
  bf16* woT   = (bf16*)alloc((size_t)1024 * 1024 * 2);
  bf16* sw1T  = (bf16*)alloc((size_t)HIDDEN * 1024 * 2);
  bf16* sw3T  = (bf16*)alloc((size_t)HIDDEN * 1024 * 2);
  bf16* sw2T  = (bf16*)alloc((size_t)1024 * HIDP * 2);
  bf16* ew1T  = (bf16*)alloc((size_t)NEXP * HIDDEN * 1024 * 2);
  bf16* ew3T  = (bf16*)alloc((size_t)NEXP * HIDDEN * 1024 * 2);
  bf16* ew2T  = (bf16*)alloc((size_t)NEXP * 1024 * HIDP * 2);
  bf16* xn    = (bf16*)alloc((size_t)TTOK * DM * 2);
  float* qkv  = (float*)alloc((size_t)TTOK * 1536 * 4);
  bf16* qb    = (bf16*)alloc((size_t)TTOK * DM * 2);
  bf16* kb    = (bf16*)alloc((size_t)TTOK * 256 * 2);
  bf16* vb    = (bf16*)alloc((size_t)TTOK * 256 * 2);
  bf16* ao    = (bf16*)alloc((size_t)TTOK * DM * 2);
  float* hbuf = (float*)alloc((size_t)TTOK * DM * 4);
  bf16* hn    = (bf16*)alloc((size_t)TTOK * DM * 2);
  float* probs = (float*)alloc((size_t)TTOK * 8 * 4);
  int*   tIdx  = (int*)alloc((size_t)TTOK * 2 * 4);
  float* tW    = (float*)alloc((size_t)TTOK * 2 * 4);
  int*   tokList = (int*)alloc((size_t)NSLOT * 4);
  float* gateW   = (float*)alloc((size_t)NSLOT * 4);
  int*   neCnt   = (int*)alloc(64);
  bf16* mh1  = (bf16*)alloc((size_t)NSLOT * HIDDEN * 2);
  bf16* mh3  = (bf16*)alloc((size_t)NSLOT * HIDDEN * 2);
  bf16* mact = (bf16*)alloc((size_t)NSLOT * HIDP * 2);

  // ---- weight convert + transpose (f32 KxN -> bf16 NxK, zero-pad K)
  transpose_cvt<<<dim3(32, 32, 1), 256, 0, stream>>>(wq, wqkvT, 1024, 1024, 1024, 0, 0);
  transpose_cvt<<<dim3(8, 32, 1), 256, 0, stream>>>(wk, wqkvT + (size_t)1024 * 1024, 1024, 256, 1024, 0, 0);
  transpose_cvt<<<dim3(8, 32, 1), 256, 0, stream>>>(wv, wqkvT + (size_t)1280 * 1024, 1024, 256, 1024, 0, 0);
  transpose_cvt<<<dim3(32, 32, 1), 256, 0, stream>>>(wo, woT, 1024, 1024, 1024, 0, 0);
  transpose_cvt<<<dim3(43, 32, 1), 256, 0, stream>>>(sw1, sw1T, 1024, HIDDEN, 1024, 0, 0);
  transpose_cvt<<<dim3(43, 32, 1), 256, 0, stream>>>(sw3, sw3T, 1024, HIDDEN, 1024, 0, 0);
  transpose_cvt<<<dim3(32, 44, 1), 256, 0, stream>>>(sw2, sw2T, HIDDEN, 1024, HIDP, 0, 0);
  transpose_cvt<<<dim3(43, 32, NEXP), 256, 0, stream>>>(ew1, ew1T, 1024, HIDDEN, 1024,
      (long)1024 * HIDDEN, (long)HIDDEN * 1024);
  transpose_cvt<<<dim3(43, 32, NEXP), 256, 0, stream>>>(ew3, ew3T, 1024, HIDDEN, 1024,
      (long)1024 * HIDDEN, (long)HIDDEN * 1024);
  transpose_cvt<<<dim3(32, 44, NEXP), 256, 0, stream>>>(ew2, ew2T, HIDDEN, 1024, HIDP,
      (long)HIDDEN * 1024, (long)1024 * HIDP);

  // ---- attention path
  rmsnorm_kernel<<<TTOK, 256, 0, stream>>>(x, attnw, xn);
  gemm_bt<0, false, false><<<dim3(32, 12), 256, 0, stream>>>(
      xn, wqkvT, TTOK, 1536, 1024, 1024, 1024, 0L,
      qkv, nullptr, 1536, nullptr, nullptr, nullptr, nullptr, nullptr);
  rope_kernel<<<TTOK, 256, 0, stream>>>(qkv, cosb, sinb, qb, kb, vb, newk, newv);
  attn_kernel<<<dim3(32, NHEAD, 2), 256, 0, stream>>>(qb, kb, vb, ao);
  gemm_bt<2, false, false><<<dim3(32, 8), 256, 0, stream>>>(
      ao, woT, TTOK, 1024, 1024, 1024, 1024, 0L,
      hbuf, nullptr, 1024, x, nullptr, nullptr, nullptr, nullptr);

  // ---- MoE routing
  rmsnorm_kernel<<<TTOK, 256, 0, stream>>>(hbuf, moew, hn);
  router_kernel<<<TTOK, 64, 0, stream>>>(hn, rw, probs, tIdx, tW);
  assign_kernel<<<1, 256, 0, stream>>>(probs, tIdx, tW, tokList, gateW, neCnt, auxp);

  // ---- shared expert: out = h + silu(hn@sw1)*(hn@sw3) @ sw2
  gemm_bt<1, false, false><<<dim3(32, 11), 256, 0, stream>>>(
      hn, sw1T, TTOK, HIDDEN, 1024, 1024, 1024, 0L,
      nullptr, mh1, HIDDEN, nullptr, nullptr, nullptr, nullptr, nullptr);
  gemm_bt<1, false, false><<<dim3(32, 11), 256, 0, stream>>>(
      hn, sw3T, TTOK, HIDDEN, 1024, 1024, 1024, 0L,
      nullptr, mh3, HIDDEN, nullptr, nullptr, nullptr, nullptr, nullptr);
  act_kernel<<<(TTOK * HIDP + 255) / 256, 256, 0, stream>>>(mh1, mh3, mact, TTOK);
  gemm_bt<2, false, false><<<dim3(32, 8), 256, 0, stream>>>(
      mact, sw2T, TTOK, 1024, HIDP, HIDP, HIDP, 0L,
      outp, nullptr, 1024, hbuf, nullptr, nullptr, nullptr, nullptr);

  // ---- routed experts (gathered, capacity-compacted), scatter-add into out
  gemm_bt<1, true, true><<<dim3(NSLOT / 128, 11), 256, 0, stream>>>(
      hn, ew1T, NSLOT, HIDDEN, 1024, 1024, 1024, (long)HIDDEN * 1024,
      nullptr, mh1, HIDDEN, nullptr, tokList, neCnt, nullptr, nullptr);
  gemm_bt<1, true, true><<<dim3(NSLOT / 128, 11), 256, 0, stream>>>(
      hn, ew3T, NSLOT, HIDDEN, 1024, 1024, 1024, (long)HIDDEN * 1024,
      nullptr, mh3, HIDDEN, nullptr, tokList, neCnt, nullptr, nullptr);
  act_kernel<<<(NSLOT * HIDP + 255) / 256, 256, 0, stream>>>(mh1, mh3, mact, NSLOT);
  gemm_bt<3, false, true><<<dim3(NSLOT / 128, 8), 256, 0, stream>>>(
      mact, ew2T, NSLOT, 1024, HIDP, HIDP, HIDP, (long)1024 * HIDP,
      nullptr, nullptr, 1024, nullptr, tokList, neCnt, gateW, outp);
}

// Round 3
// 831.462 us; speedup vs baseline: 1.1942x; 1.1942x over previous
//
#include <hip/hip_runtime.h>
#include <hip/hip_bf16.h>
#include <math.h>

typedef __hip_bfloat16 bf16;
typedef __attribute__((ext_vector_type(8))) short short8;
typedef __attribute__((ext_vector_type(4))) float floatx4;

#define SEQ    2048
#define TTOK   4096
#define DM     1024
#define NHEAD  16
#define NKVH   4
#define HD     64
#define NEXP   8
#define HIDDEN 1365
#define HIDP   1408
#define CAPT   1280
#define NSLOT  (NEXP*CAPT)   /* 10240 */

// ---------------------------------------------------------------- utilities
__device__ __forceinline__ void gld16(const void* g, void* l) {
  // async global->LDS, 16B per lane; LDS dest = wave-uniform base + lane*16
  __builtin_amdgcn_global_load_lds((const __attribute__((address_space(1))) void*)g,
                                   (__attribute__((address_space(3))) void*)l,
                                   16, 0, 0);
}

struct __align__(8) bf4 { bf16 x, y, z, w; };

struct EpiAux {
  const float* cosb; const float* sinb;
  bf16* qb; bf16* kb; bf16* vb; float* newk; float* newv;
  const bf16* h1; int ldh1;
};

// ---------------------------------------------------- weight convert+transpose
// src: (K,N) f32 row-major -> dst: (N,Kp) bf16 row-major, zero-fill k in [K,Kp)
__global__ __launch_bounds__(256) void transpose_cvt(
    const float* __restrict__ src, bf16* __restrict__ dst,
    int K, int N, int Kp, long srcZ, long dstZ) {
  src += (size_t)blockIdx.z * srcZ;
  dst += (size_t)blockIdx.z * dstZ;
  __shared__ float tile[32][33];
  int tid = threadIdx.x;
  int tx = tid & 31, ty = tid >> 5;            // 32 x 8
  int k0 = blockIdx.y * 32, n0 = blockIdx.x * 32;
#pragma unroll
  for (int i = 0; i < 4; ++i) {
    int k = k0 + ty + i * 8, n = n0 + tx;
    tile[ty + i * 8][tx] = (k < K && n < N) ? src[(size_t)k * N + n] : 0.f;
  }
  __syncthreads();
#pragma unroll
  for (int i = 0; i < 4; ++i) {
    int n = n0 + ty + i * 8, k = k0 + tx;
    if (n < N && k < Kp) dst[(size_t)n * Kp + k] = (bf16)tile[tx][ty + i * 8];
  }
}

// ---------------------------------------------------------------- rmsnorm
__global__ __launch_bounds__(256) void rmsnorm_kernel(
    const float* __restrict__ x, const float* __restrict__ w, bf16* __restrict__ out) {
  int t = blockIdx.x;
  const float* xr = x + (size_t)t * DM;
  float4 xv = *(const float4*)(xr + threadIdx.x * 4);
  float ss = xv.x * xv.x + xv.y * xv.y + xv.z * xv.z + xv.w * xv.w;
#pragma unroll
  for (int off = 1; off < 64; off <<= 1) ss += __shfl_xor(ss, off);
  __shared__ float sred[4];
  if ((threadIdx.x & 63) == 0) sred[threadIdx.x >> 6] = ss;
  __syncthreads();
  float scale = rsqrtf((sred[0] + sred[1] + sred[2] + sred[3]) * (1.f / DM) + 1e-6f);
  float4 wv = *(const float4*)(w + threadIdx.x * 4);
  bf4 o;
  o.x = (bf16)(xv.x * scale * wv.x); o.y = (bf16)(xv.y * scale * wv.y);
  o.z = (bf16)(xv.z * scale * wv.z); o.w = (bf16)(xv.w * scale * wv.w);
  ((bf4*)(out + (size_t)t * DM))[threadIdx.x] = o;
}

// -------------------------------------------- rmsnorm + router (moe path)
__global__ __launch_bounds__(256) void rmsnorm_router_kernel(
    const float* __restrict__ x, const float* __restrict__ w, const float* __restrict__ rw,
    bf16* __restrict__ out, float* __restrict__ probs,
    int* __restrict__ tIdx, float* __restrict__ tW) {
  int t = blockIdx.x;
  int tid = threadIdx.x, lane = tid & 63, wv = tid >> 6;
  const float* xr = x + (size_t)t * DM;
  float4 xv = *(const float4*)(xr + tid * 4);
  float ss = xv.x * xv.x + xv.y * xv.y + xv.z * xv.z + xv.w * xv.w;
#pragma unroll
  for (int off = 1; off < 64; off <<= 1) ss += __shfl_xor(ss, off);
  __shared__ float sred[4];
  __shared__ float red[4][8];
  if (lane == 0) sred[wv] = ss;
  __syncthreads();
  float scale = rsqrtf((sred[0] + sred[1] + sred[2] + sred[3]) * (1.f / DM) + 1e-6f);
  float4 wvv = *(const float4*)(w + tid * 4);
  float y[4] = {xv.x * scale * wvv.x, xv.y * scale * wvv.y,
                xv.z * scale * wvv.z, xv.w * scale * wvv.w};
  bf4 o; o.x = (bf16)y[0]; o.y = (bf16)y[1]; o.z = (bf16)y[2]; o.w = (bf16)y[3];
  ((bf4*)(out + (size_t)t * DM))[tid] = o;
  // router logits
  float acc[8] = {0, 0, 0, 0, 0, 0, 0, 0};
#pragma unroll
  for (int dd = 0; dd < 4; ++dd) {
    const float* rwr = rw + (size_t)(tid * 4 + dd) * 8;
#pragma unroll
    for (int e = 0; e < 8; ++e) acc[e] += y[dd] * rwr[e];
  }
#pragma unroll
  for (int e = 0; e < 8; ++e)
#pragma unroll
    for (int off = 1; off < 64; off <<= 1) acc[e] += __shfl_xor(acc[e], off);
  if (lane == 0)
#pragma unroll
    for (int e = 0; e < 8; ++e) red[wv][e] = acc[e];
  __syncthreads();
  if (tid == 0) {
    float lg[8];
#pragma unroll
    for (int e = 0; e < 8; ++e) lg[e] = red[0][e] + red[1][e] + red[2][e] + red[3][e];
    float mx = lg[0];
#pragma unroll
    for (int e = 1; e < 8; ++e) mx = fmaxf(mx, lg[e]);
    float p[8], se = 0.f;
#pragma unroll
    for (int e = 0; e < 8; ++e) { p[e] = __expf(lg[e] - mx); se += p[e]; }
#pragma unroll
    for (int e = 0; e < 8; ++e) { p[e] /= se; probs[t * 8 + e] = p[e]; }
    int i1 = 0;
#pragma unroll
    for (int e = 1; e < 8; ++e) if (p[e] > p[i1]) i1 = e;
    int i2 = (i1 == 0) ? 1 : 0;
#pragma unroll
    for (int e = 0; e < 8; ++e) if (e != i1 && p[e] > p[i2]) i2 = e;
    float s = p[i1] + p[i2];
    tIdx[t * 2] = i1; tIdx[t * 2 + 1] = i2;
    tW[t * 2] = p[i1] / s; tW[t * 2 + 1] = p[i2] / s;
  }
}

// ---------------------------------------------------------------- GEMM
// C(MxN) = A(MxK) @ Bt(NxK)^T ; 128x128 tile, BK=64, 4 waves, 16x16x32 bf16 MFMA
// EPI: 1 = Cb bf16 store ; 2 = Cf = resid + acc ;
//      3 = atomicAdd(scatOut[tok[row]*ldc+col], gateW[row]*acc) ;
//      4 = QKV + rope epilogue ; 5 = Cb = silu(h1)*acc (bf16)
template <int EPI, bool GATHER, bool MOE>
__global__ __launch_bounds__(256) void gemm_bt(
    const bf16* __restrict__ A, const bf16* __restrict__ Bt,
    int M, int N, int K, int lda, int ldb, long bStrideE,
    float* __restrict__ Cf, bf16* __restrict__ Cb, int ldc,
    const float* __restrict__ resid,
    const int* __restrict__ tokList, const int* __restrict__ neCnt,
    const float* __restrict__ gateW, float* __restrict__ scatOut,
    EpiAux aux) {
  __shared__ __align__(16) bf16 As[128 * 64];
  __shared__ __align__(16) bf16 Bs[128 * 64];
  const int tid = threadIdx.x, lane = tid & 63, wave = tid >> 6;
  int m0, expert = 0, mLimit;
  if constexpr (MOE) {
    int slot0 = blockIdx.x * 128;
    expert = slot0 / CAPT;
    int local0 = slot0 - expert * CAPT;
    int ne = neCnt[expert];
    if (local0 >= ne) return;
    m0 = slot0;
    mLimit = ne - local0;
  } else {
    m0 = blockIdx.x * 128;
    mLimit = M - m0;
  }
  if (mLimit > 128) mLimit = 128;
  const int n0 = blockIdx.y * 128;
  const bf16* Bte = Bt + (MOE ? (long)expert * bStrideE : 0L);

  // staging: chunk c = it*256+tid covers (r = c/8, pos q = c%8),
  // holding data k-chunk kq = q ^ (r&7)  (xor swizzle)
  const bf16* aSrc[4]; const bf16* bSrc[4];
  bf16* aDst[4]; bf16* bDst[4];
#pragma unroll
  for (int it = 0; it < 4; ++it) {
    int c = it * 256 + tid;
    int r = c >> 3, q = c & 7;
    int kq = q ^ (r & 7);
    int rr = r < mLimit ? r : (mLimit - 1);
    long arow;
    if constexpr (GATHER) arow = tokList[m0 + rr];
    else arow = (long)(m0 + rr);
    aSrc[it] = A + arow * lda + kq * 8;
    int nn = n0 + r; if (nn > N - 1) nn = N - 1;
    bSrc[it] = Bte + (long)nn * ldb + kq * 8;
    aDst[it] = As + (size_t)(it * 256 + wave * 64) * 8;
    bDst[it] = Bs + (size_t)(it * 256 + wave * 64) * 8;
  }

  floatx4 acc[4][4];
#pragma unroll
  for (int i = 0; i < 4; ++i)
#pragma unroll
    for (int j = 0; j < 4; ++j) { floatx4 z = {0.f, 0.f, 0.f, 0.f}; acc[i][j] = z; }

  const int wm = (wave & 1) * 64, wn = (wave >> 1) * 64;
  const int l15 = lane & 15, quad = lane >> 4;
  int aOff[4][2], bOff[4][2];
#pragma unroll
  for (int i = 0; i < 4; ++i) {
    int m = wm + i * 16 + l15;
    int n = wn + i * 16 + l15;
#pragma unroll
    for (int h = 0; h < 2; ++h) {
      aOff[i][h] = (((m << 3) | ((h * 4 + quad) ^ (m & 7))) << 3);
      bOff[i][h] = (((n << 3) | ((h * 4 + quad) ^ (n & 7))) << 3);
    }
  }

  const int kIters = K >> 6;
  for (int kt = 0; kt < kIters; ++kt) {
    __syncthreads();
#pragma unroll
    for (int it = 0; it < 4; ++it) {
      gld16(aSrc[it], aDst[it]);
      gld16(bSrc[it], bDst[it]);
      aSrc[it] += 64; bSrc[it] += 64;
    }
    __syncthreads();
#pragma unroll
    for (int h = 0; h < 2; ++h) {
      short8 af[4], bfr[4];
#pragma unroll
      for (int i = 0; i < 4; ++i) af[i] = *(const short8*)(As + aOff[i][h]);
#pragma unroll
      for (int j = 0; j < 4; ++j) bfr[j] = *(const short8*)(Bs + bOff[j][h]);
#pragma unroll
      for (int i = 0; i < 4; ++i)
#pragma unroll
        for (int j = 0; j < 4; ++j)
          acc[i][j] = __builtin_amdgcn_mfma_f32_16x16x32_bf16(af[i], bfr[j], acc[i][j], 0, 0, 0);
    }
  }

  // epilogue: C row = quad*4+reg, col = lane&15 (m89-verified layout)
  if constexpr (EPI == 4) {
    // QKV + rope; tile regions: n0<1024 Q, n0<1280 K, else V. wn is 64-aligned.
#pragma unroll
    for (int i = 0; i < 4; ++i) {
#pragma unroll
      for (int r = 0; r < 4; ++r) {
        int row = wm + i * 16 + quad * 4 + r;
        int t = m0 + row;
        int s = t & (SEQ - 1);
        if (n0 < 1024) {
#pragma unroll
          for (int j = 0; j < 2; ++j) {
            int col = n0 + wn + j * 16 + l15;
            int dlo = col & 63;           // < 32 for j in {0,1}
            float x1 = acc[i][j][r], x2 = acc[i][j + 2][r];
            float ch = aux.cosb[s * 64 + dlo], sh = aux.sinb[s * 64 + dlo];
            // fold 1/sqrt(64) = 0.125 (exact pow2) into Q
            aux.qb[(size_t)t * DM + col]      = (bf16)((x1 * ch - x2 * sh) * 0.125f);
            aux.qb[(size_t)t * DM + col + 32] = (bf16)((x1 * sh + x2 * ch) * 0.125f);
          }
        } else if (n0 < 1280) {
#pragma unroll
          for (int j = 0; j < 2; ++j) {
            int ck = n0 + wn + j * 16 + l15 - 1024;
            int dlo = ck & 63;
            float x1 = acc[i][j][r], x2 = acc[i][j + 2][r];
            float ch = aux.cosb[s * 64 + dlo], sh = aux.sinb[s * 64 + dlo];
            float o1 = x1 * ch - x2 * sh, o2 = x1 * sh + x2 * ch;
            aux.kb[(size_t)t * 256 + ck]        = (bf16)o1;
            aux.kb[(size_t)t * 256 + ck + 32]   = (bf16)o2;
            aux.newk[(size_t)t * 256 + ck]      = o1;
            aux.newk[(size_t)t * 256 + ck + 32] = o2;
          }
        } else {
#pragma unroll
          for (int j = 0; j < 4; ++j) {
            int cv = n0 + wn + j * 16 + l15 - 1280;
            float v = acc[i][j][r];
            aux.vb[(size_t)t * 256 + cv]   = (bf16)v;
            aux.newv[(size_t)t * 256 + cv] = v;
          }
        }
      }
    }
    return;
  }
#pragma unroll
  for (int i = 0; i < 4; ++i) {
#pragma unroll
    for (int j = 0; j < 4; ++j) {
      int col = n0 + wn + j * 16 + l15;
#pragma unroll
      for (int r = 0; r < 4; ++r) {
        int row = wm + i * 16 + quad * 4 + r;
        if (row >= mLimit || col >= N) continue;
        float v = acc[i][j][r];
        if constexpr (EPI == 1) {
          Cb[(size_t)(m0 + row) * ldc + col] = (bf16)v;
        } else if constexpr (EPI == 2) {
          size_t o = (size_t)(m0 + row) * ldc + col;
          Cf[o] = resid[o] + v;
        } else if constexpr (EPI == 3) {
          int tok = tokList[m0 + row];
          atomicAdd(&scatOut[(size_t)tok * ldc + col], gateW[m0 + row] * v);
        } else if constexpr (EPI == 5) {
          float h1v = (float)aux.h1[(size_t)(m0 + row) * aux.ldh1 + col];
          float sl = h1v / (1.f + __expf(-h1v));
          Cb[(size_t)(m0 + row) * ldc + col] = (bf16)(sl * v);
        }
      }
    }
  }
}

// ------------------------------------------- V transpose: vb[t][256] -> vt[bg][d][s]
__global__ __launch_bounds__(256) void vt_kernel(
    const bf16* __restrict__ vb, bf16* __restrict__ vt) {
  __shared__ __align__(16) bf16 tile[64 * 72];
  int t0 = blockIdx.x * 64, bg = blockIdx.y;
  int b = bg >> 2, g = bg & 3;
  int tid = threadIdx.x;
  for (int c = tid; c < 512; c += 256) {
    int r = c >> 3, d8 = (c & 7) * 8;
    *(short8*)(tile + r * 72 + d8) =
        *(const short8*)(vb + (size_t)(b * SEQ + t0 + r) * 256 + g * 64 + d8);
  }
  __syncthreads();
  for (int c = tid; c < 512; c += 256) {
    int d = c >> 3, s8 = (c & 7) * 8;
    bf16 tmp[8];
#pragma unroll
    for (int x = 0; x < 8; ++x) tmp[x] = tile[(s8 + x) * 72 + d];
    *(short8*)(vt + ((size_t)bg * 64 + d) * SEQ + t0 + s8) = *(short8*)tmp;
  }
}

// ---------------------------------------------------------------- flash attention
// Q pre-scaled by 0.125. All tiles staged via global_load_lds with XOR chunk swizzle.
__global__ __launch_bounds__(256) void attn_kernel(
    const bf16* __restrict__ Q, const bf16* __restrict__ Kc, const bf16* __restrict__ Vt,
    bf16* __restrict__ AO) {
  __shared__ __align__(16) bf16 Qs[64 * 64];
  __shared__ __align__(16) bf16 Ks[64 * 64];
  __shared__ __align__(16) bf16 Vs[64 * 64];   // Vs[d][k] (k = token within tile)
  __shared__ __align__(16) bf16 Ps[4][16 * 64];
  const int q0 = blockIdx.x * 64, h = blockIdx.y, b = blockIdx.z;
  const int g = h >> 2;
  const int tid = threadIdx.x, lane = tid & 63, wave = tid >> 6;
  const int l15 = lane & 15, quad = lane >> 4;

  // Q staging (once)
#pragma unroll
  for (int it = 0; it < 2; ++it) {
    int c = it * 256 + tid;
    int r = c >> 3, p = c & 7;
    int kq = p ^ (r & 7);
    gld16(Q + (size_t)(b * SEQ + q0 + r) * DM + h * 64 + kq * 8,
          Qs + (size_t)(it * 256 + wave * 64) * 8);
  }

  // K/V staging bases
  const bf16* kSrc[2]; const bf16* vSrc[2]; bf16* kDst[2]; bf16* vDst[2];
#pragma unroll
  for (int it = 0; it < 2; ++it) {
    int c = it * 256 + tid;
    int r = c >> 3, p = c & 7;
    int kq = p ^ (r & 7);
    kSrc[it] = Kc + (size_t)(b * SEQ + r) * 256 + g * 64 + kq * 8;
    vSrc[it] = Vt + ((size_t)(b * 4 + g) * 64 + r) * SEQ + kq * 8;
    kDst[it] = Ks + (size_t)(it * 256 + wave * 64) * 8;
    vDst[it] = Vs + (size_t)(it * 256 + wave * 64) * 8;
  }

  // fragment offsets
  int qOff[2], kvOff[4][2], pOff[2];
#pragma unroll
  for (int hh = 0; hh < 2; ++hh) {
    int m = wave * 16 + l15;
    qOff[hh] = (m << 6) + (((hh * 4 + quad) ^ (m & 7)) << 3);
#pragma unroll
    for (int j = 0; j < 4; ++j) {
      int n = j * 16 + l15;
      kvOff[j][hh] = (n << 6) + (((hh * 4 + quad) ^ (n & 7)) << 3);
    }
    int cblk = (hh * 2 + (quad >> 1)) ^ (l15 >> 2);
    pOff[hh] = (l15 << 6) + (cblk << 4) + ((quad & 1) << 3);
  }
  bf16* pw = &Ps[wave][0];

  float m_i[4], l_i[4];
  floatx4 oacc[4];
#pragma unroll
  for (int r = 0; r < 4; ++r) {
    m_i[r] = -1e30f; l_i[r] = 0.f;
    floatx4 z = {0.f, 0.f, 0.f, 0.f}; oacc[r] = z;
  }

  const int nkt = (q0 >> 6) + 1;
  const int rowl = wave * 16 + quad * 4;
  for (int kt = 0; kt < nkt; ++kt) {
    __syncthreads();
#pragma unroll
    for (int it = 0; it < 2; ++it) {
      gld16(kSrc[it] + (size_t)kt * 64 * 256, kDst[it]);
      gld16(vSrc[it] + kt * 64, vDst[it]);
    }
    __syncthreads();

    // S = Q K^T (Q pre-scaled)
    floatx4 sacc[4];
#pragma unroll
    for (int j = 0; j < 4; ++j) { floatx4 z = {0.f, 0.f, 0.f, 0.f}; sacc[j] = z; }
#pragma unroll
    for (int hh = 0; hh < 2; ++hh) {
      short8 aq = *(const short8*)(Qs + qOff[hh]);
#pragma unroll
      for (int j = 0; j < 4; ++j)
        sacc[j] = __builtin_amdgcn_mfma_f32_16x16x32_bf16(
            aq, *(const short8*)(Ks + kvOff[j][hh]), sacc[j], 0, 0, 0);
    }

    if (kt == nkt - 1) {   // only diagonal tile needs causal mask
#pragma unroll
      for (int j = 0; j < 4; ++j) {
        int colg = j * 16 + l15;
#pragma unroll
        for (int r = 0; r < 4; ++r)
          if (colg > rowl + r) sacc[j][r] = -1e30f;
      }
    }

    // online softmax
    float mnew[4];
#pragma unroll
    for (int r = 0; r < 4; ++r) {
      mnew[r] = m_i[r];
#pragma unroll
      for (int j = 0; j < 4; ++j) mnew[r] = fmaxf(mnew[r], sacc[j][r]);
    }
#pragma unroll
    for (int r = 0; r < 4; ++r)
#pragma unroll
      for (int off = 1; off < 16; off <<= 1) mnew[r] = fmaxf(mnew[r], __shfl_xor(mnew[r], off));
    float alpha[4], psum[4];
#pragma unroll
    for (int r = 0; r < 4; ++r) {
      alpha[r] = __expf(m_i[r] - mnew[r]);
      m_i[r] = mnew[r]; psum[r] = 0.f;
    }
#pragma unroll
    for (int j = 0; j < 4; ++j) {
      int sw = ((j ^ quad) << 4) + l15;   // XOR-block swizzle: conflict-free stores
#pragma unroll
      for (int r = 0; r < 4; ++r) {
        float p = __expf(sacc[j][r] - m_i[r]);
        psum[r] += p;
        pw[(quad * 4 + r) * 64 + sw] = (bf16)p;
      }
    }
#pragma unroll
    for (int r = 0; r < 4; ++r) {
#pragma unroll
      for (int off = 1; off < 16; off <<= 1) psum[r] += __shfl_xor(psum[r], off);
      l_i[r] = l_i[r] * alpha[r] + psum[r];
    }
#pragma unroll
    for (int j = 0; j < 4; ++j)
#pragma unroll
      for (int r = 0; r < 4; ++r) oacc[j][r] *= alpha[r];
    asm volatile("s_waitcnt lgkmcnt(0)" ::: "memory");   // P stores -> visible (same wave)
#pragma unroll
    for (int hh = 0; hh < 2; ++hh) {
      short8 ap = *(const short8*)(pw + pOff[hh]);
#pragma unroll
      for (int j = 0; j < 4; ++j)
        oacc[j] = __builtin_amdgcn_mfma_f32_16x16x32_bf16(
            ap, *(const short8*)(Vs + kvOff[j][hh]), oacc[j], 0, 0, 0);
    }
  }
#pragma unroll
  for (int j = 0; j < 4; ++j)
#pragma unroll
    for (int r = 0; r < 4; ++r) {
      int t = b * SEQ + q0 + rowl + r;
      AO[(size_t)t * DM + h * 64 + j * 16 + l15] = (bf16)(oacc[j][r] / l_i[r]);
    }
}

// ------------------------------------------------- capacity assignment (8 blocks)
__global__ __launch_bounds__(256) void assign_kernel(
    const int* __restrict__ tIdx, const float* __restrict__ tW,
    int* __restrict__ tokList, float* __restrict__ gateW,
    int* __restrict__ neCnt, int* __restrict__ cntFull) {
  int e = blockIdx.x;
  __shared__ int waveTot[4];
  __shared__ int offs;
  int tid = threadIdx.x, lane = tid & 63, wv = tid >> 6;
  if (tid == 0) offs = 0;
  __syncthreads();
  for (int base = 0; base < TTOK; base += 256) {
    int t = base + tid;
    int a = tIdx[t * 2], b2 = tIdx[t * 2 + 1];
    bool sel = (a == e) || (b2 == e);
    unsigned long long mask = __ballot(sel);
    int wrank = __popcll(mask & ((1ull << lane) - 1ull));
    if (lane == 0) waveTot[wv] = __popcll(mask);
    __syncthreads();
    int pre = offs;
    for (int w2 = 0; w2 < wv; ++w2) pre += waveTot[w2];
    int rank = pre + wrank;
    if (sel && rank < CAPT) {
      tokList[e * CAPT + rank] = t;
      gateW[e * CAPT + rank] = (a == e) ? tW[t * 2] : tW[t * 2 + 1];
    }
    __syncthreads();
    if (tid == 0) offs += waveTot[0] + waveTot[1] + waveTot[2] + waveTot[3];
    __syncthreads();
  }
  if (tid == 0) {
    cntFull[e] = offs;
    neCnt[e] = offs < CAPT ? offs : CAPT;
  }
}

// ---------------------------------------------------------------- aux loss / util
__global__ __launch_bounds__(256) void aux_kernel(
    const float* __restrict__ probs, const int* __restrict__ cntFull,
    float* __restrict__ outAux) {
  __shared__ float psum[8];
  if (threadIdx.x < 8) psum[threadIdx.x] = 0.f;
  __syncthreads();
  float lp[8] = {0, 0, 0, 0, 0, 0, 0, 0};
  for (int t = threadIdx.x; t < TTOK; t += 256) {
#pragma unroll
    for (int e = 0; e < 8; ++e) lp[e] += probs[t * 8 + e];
  }
#pragma unroll
  for (int e = 0; e < 8; ++e)
#pragma unroll
    for (int off = 1; off < 64; off <<= 1) lp[e] += __shfl_xor(lp[e], off);
  if ((threadIdx.x & 63) == 0)
#pragma unroll
    for (int e = 0; e < 8; ++e) atomicAdd(&psum[e], lp[e]);
  __syncthreads();
  if (threadIdx.x == 0) {
    float aux = 0.f; int used = 0;
    for (int e = 0; e < 8; ++e) {
      aux += (psum[e] / (float)TTOK) * ((float)cntFull[e] / (float)TTOK);
      if (cntFull[e] > 0) used++;
    }
    outAux[0] = 8.f * aux;
    outAux[1] = 100.f * (float)used / 8.f;
  }
}

// ---------------------------------------------------------------- launch
extern "C" void kernel_launch(void* const* d_in, const int* in_sizes, int n_in,
                              void* d_out, int out_size, void* d_ws, size_t ws_size,
                              hipStream_t stream) {
  (void)in_sizes; (void)n_in; (void)out_size; (void)ws_size;
  const float* x     = (const float*)d_in[0];
  const float* cosb  = (const float*)d_in[1];
  const float* sinb  = (const float*)d_in[2];
  const float* attnw = (const float*)d_in[4];
  const float* moew  = (const float*)d_in[5];
  const float* wq  = (const float*)d_in[6];
  const float* wk  = (const float*)d_in[7];
  const float* wv  = (const float*)d_in[8];
  const float* wo  = (const float*)d_in[9];
  const float* rw  = (const float*)d_in[10];
  const float* ew1 = (const float*)d_in[11];
  const float* ew2 = (const float*)d_in[12];
  const float* ew3 = (const float*)d_in[13];
  const float* sw1 = (const float*)d_in[14];
  const float* sw2 = (const float*)d_in[15];
  const float* sw3 = (const float*)d_in[16];

  float* outp = (float*)d_out;
  float* auxp = outp + 4194304;
  float* newk = outp + 4194306;
  float* newv = newk + 1048576;

  char* wsp = (char*)d_ws;
  size_t off = 0;
  auto alloc = [&](size_t bytes) -> void* {
    void* p = wsp + off; off += (bytes + 255) & ~(size_t)255; return p;
  };
  bf16* wqkvT = (bf16*)alloc((size_t)1536 * 1024 * 2);
  bf16* woT   = (bf16*)alloc((size_t)1024 * 1024 * 2);
  bf16* sw1T  = (bf16*)alloc((size_t)HIDDEN * 1024 * 2);
  bf16* sw3T  = (bf16*)alloc((size_t)HIDDEN * 1024 * 2);
  bf16* sw2T  = (bf16*)alloc((size_t)1024 * HIDP * 2);
  bf16* ew1T  = (bf16*)alloc((size_t)NEXP * HIDDEN * 1024 * 2);
  bf16* ew3T  = (bf16*)alloc((size_t)NEXP * HIDDEN * 1024 * 2);
  bf16* ew2T  = (bf16*)alloc((size_t)NEXP * 1024 * HIDP * 2);
  bf16* xn    = (bf16*)alloc((size_t)TTOK * DM * 2);
  bf16* qb    = (bf16*)alloc((size_t)TTOK * DM * 2);
  bf16* kb    = (bf16*)alloc((size_t)TTOK * 256 * 2);
  bf16* vb    = (bf16*)alloc((size_t)TTOK * 256 * 2);
  bf16* vt    = (bf16*)alloc((size_t)TTOK * 256 * 2);
  bf16* ao    = (bf16*)alloc((size_t)TTOK * DM * 2);
  float* hbuf = (float*)alloc((size_t)TTOK * DM * 4);
  bf16* hn    = (bf16*)alloc((size_t)TTOK * DM * 2);
  float* probs = (float*)alloc((size_t)TTOK * 8 * 4);
  int*   tIdx  = (int*)alloc((size_t)TTOK * 2 * 4);
  float* tW    = (float*)alloc((size_t)TTOK * 2 * 4);
  int*   tokList = (int*)alloc((size_t)NSLOT * 4);
  float* gateW   = (float*)alloc((size_t)NSLOT * 4);
  int*   neCnt   = (int*)alloc(64);
  int*   cntFull = (int*)alloc(64);
  bf16* mh1  = (bf16*)alloc((size_t)NSLOT * HIDDEN * 2);
  bf16* mact = (bf16*)alloc((size_t)NSLOT * HIDP * 2);

  EpiAux nil{};
  EpiAux ropeAux{cosb, sinb, qb, kb, vb, newk, newv, nullptr, 0};

  // ---- weight convert + transpose (f32 KxN -> bf16 NxK, zero-pad K)
  transpose_cvt<<<dim3(32, 32, 1), 256, 0, stream>>>(wq, wqkvT, 1024, 1024, 1024, 0, 0);
  transpose_cvt<<<dim3(8, 32, 1), 256, 0, stream>>>(wk, wqkvT + (size_t)1024 * 1024, 1024, 256, 1024, 0, 0);
  transpose_cvt<<<dim3(8, 32, 1), 256, 0, stream>>>(wv, wqkvT + (size_t)1280 * 1024, 1024, 256, 1024, 0, 0);
  transpose_cvt<<<dim3(32, 32, 1), 256, 0, stream>>>(wo, woT, 1024, 1024, 1024, 0, 0);
  transpose_cvt<<<dim3(43, 32, 1), 256, 0, stream>>>(sw1, sw1T, 1024, HIDDEN, 1024, 0, 0);
  transpose_cvt<<<dim3(43, 32, 1), 256, 0, stream>>>(sw3, sw3T, 1024, HIDDEN, 1024, 0, 0);
  transpose_cvt<<<dim3(32, 44, 1), 256, 0, stream>>>(sw2, sw2T, HIDDEN, 1024, HIDP, 0, 0);
  transpose_cvt<<<dim3(43, 32, NEXP), 256, 0, stream>>>(ew1, ew1T, 1024, HIDDEN, 1024,
      (long)1024 * HIDDEN, (long)HIDDEN * 1024);
  transpose_cvt<<<dim3(43, 32, NEXP), 256, 0, stream>>>(ew3, ew3T, 1024, HIDDEN, 1024,
      (long)1024 * HIDDEN, (long)HIDDEN * 1024);
  transpose_cvt<<<dim3(32, 44, NEXP), 256, 0, stream>>>(ew2, ew2T, HIDDEN, 1024, HIDP,
      (long)HIDDEN * 1024, (long)1024 * HIDP);

  // ---- attention path
  rmsnorm_kernel<<<TTOK, 256, 0, stream>>>(x, attnw, xn);
  gemm_bt<4, false, false><<<dim3(32, 12), 256, 0, stream>>>(
      xn, wqkvT, TTOK, 1536, 1024, 1024, 1024, 0L,
      nullptr, nullptr, 0, nullptr, nullptr, nullptr, nullptr, nullptr, ropeAux);
  vt_kernel<<<dim3(32, 8), 256, 0, stream>>>(vb, vt);
  attn_kernel<<<dim3(32, NHEAD, 2), 256, 0, stream>>>(qb, kb, vt, ao);
  gemm_bt<2, false, false><<<dim3(32, 8), 256, 0, stream>>>(
      ao, woT, TTOK, 1024, 1024, 1024, 1024, 0L,
      hbuf, nullptr, 1024, x, nullptr, nullptr, nullptr, nullptr, nil);

  // ---- MoE routing
  rmsnorm_router_kernel<<<TTOK, 256, 0, stream>>>(hbuf, moew, rw, hn, probs, tIdx, tW);
  assign_kernel<<<NEXP, 256, 0, stream>>>(tIdx, tW, tokList, gateW, neCnt, cntFull);
  aux_kernel<<<1, 256, 0, stream>>>(probs, cntFull, auxp);

  // ---- shared expert: out = h + silu(hn@sw1)*(hn@sw3) @ sw2
  gemm_bt<1, false, false><<<dim3(32, 11), 256, 0, stream>>>(
      hn, sw1T, TTOK, HIDDEN, 1024, 1024, 1024, 0L,
      nullptr, mh1, HIDDEN, nullptr, nullptr, nullptr, nullptr, nullptr, nil);
  {
    EpiAux a5{nullptr, nullptr, nullptr, nullptr, nullptr, nullptr, nullptr, mh1, HIDDEN};
    gemm_bt<5, false, false><<<dim3(32, 11), 256, 0, stream>>>(
        hn, sw3T, TTOK, HIDDEN, 1024, 1024, 1024, 0L,
        nullptr, mact, HIDP, nullptr, nullptr, nullptr, nullptr, nullptr, a5);
  }
  gemm_bt<2, false, false><<<dim3(32, 8), 256, 0, stream>>>(
      mact, sw2T, TTOK, 1024, HIDP, HIDP, HIDP, 0L,
      outp, nullptr, 1024, hbuf, nullptr, nullptr, nullptr, nullptr, nil);

  // ---- routed experts (gathered, capacity-compacted), scatter-add into out
  gemm_bt<1, true, true><<<dim3(NSLOT / 128, 11), 256, 0, stream>>>(
      hn, ew1T, NSLOT, HIDDEN, 1024, 1024, 1024, (long)HIDDEN * 1024,
      nullptr, mh1, HIDDEN, nullptr, tokList, neCnt, nullptr, nullptr, nil);
  {
    EpiAux a5{nullptr, nullptr, nullptr, nullptr, nullptr, nullptr, nullptr, mh1, HIDDEN};
    gemm_bt<5, true, true><<<dim3(NSLOT / 128, 11), 256, 0, stream>>>(
        hn, ew3T, NSLOT, HIDDEN, 1024, 1024, 1024, (long)HIDDEN * 1024,
        nullptr, mact, HIDP, nullptr, tokList, neCnt, nullptr, nullptr, a5);
  }
  gemm_bt<3, false, true><<<dim3(NSLOT / 128, 8), 256, 0, stream>>>(
      mact, ew2T, NSLOT, 1024, HIDP, HIDP, HIDP, (long)1024 * HIDP,
      nullptr, nullptr, 1024, nullptr, tokList, neCnt, gateW, outp, nil);
}

// Round 4
// 749.931 us; speedup vs baseline: 1.3240x; 1.1087x over previous
//
#include <hip/hip_runtime.h>
#include <hip/hip_bf16.h>
#include <math.h>

typedef __hip_bfloat16 bf16;
typedef __attribute__((ext_vector_type(8))) short short8;
typedef __attribute__((ext_vector_type(4))) float floatx4;

#define SEQ    2048
#define TTOK   4096
#define DM     1024
#define NHEAD  16
#define NKVH   4
#define HD     64
#define NEXP   8
#define HIDDEN 1365
#define HIDP   1408
#define CAPT   1280
#define NSLOT  (NEXP*CAPT)   /* 10240 */

// ---------------------------------------------------------------- utilities
__device__ __forceinline__ void gld16(const void* g, void* l) {
  // async global->LDS, 16B per lane; LDS dest = wave-uniform base + lane*16
  __builtin_amdgcn_global_load_lds((const __attribute__((address_space(1))) void*)g,
                                   (__attribute__((address_space(3))) void*)l,
                                   16, 0, 0);
}

struct __align__(8) bf4 { bf16 x, y, z, w; };

struct EpiAux {
  const float* cosb; const float* sinb;
  bf16* qb; bf16* kb; bf16* vb; float* newk; float* newv;
};

// ---------------------------------------------------- weight convert+transpose
// src: (K,N) f32 row-major -> dst: (N,Kp) bf16 row-major, zero-fill k in [K,Kp)
// 64x64 tiles, float4 loads, short8 stores. Kp must be a multiple of 64.
__global__ __launch_bounds__(256) void transpose_cvt(
    const float* __restrict__ src, bf16* __restrict__ dst,
    int K, int N, int Kp, long srcZ, long dstZ) {
  src += (size_t)blockIdx.z * srcZ;
  dst += (size_t)blockIdx.z * dstZ;
  __shared__ float tile[64][65];
  const int tid = threadIdx.x;
  const int k0 = blockIdx.y * 64, n0 = blockIdx.x * 64;
  const int lr = tid >> 4, lc = (tid & 15) * 4;
#pragma unroll
  for (int i = 0; i < 4; ++i) {
    int k = k0 + lr + i * 16;
    int n = n0 + lc;
    float4 v = {0.f, 0.f, 0.f, 0.f};
    if (k < K) {
      if (n + 3 < N) v = *(const float4*)(src + (size_t)k * N + n);
      else {
        float* vp = (float*)&v;
        for (int e = 0; e < 4; ++e) if (n + e < N) vp[e] = src[(size_t)k * N + n + e];
      }
    }
    tile[lr + i * 16][lc] = v.x; tile[lr + i * 16][lc + 1] = v.y;
    tile[lr + i * 16][lc + 2] = v.z; tile[lr + i * 16][lc + 3] = v.w;
  }
  __syncthreads();
  const int n = tid >> 2, kk0 = (tid & 3) * 16;
  if (n0 + n < N) {
    bf16 buf[16];
#pragma unroll
    for (int e = 0; e < 16; ++e) buf[e] = (bf16)tile[kk0 + e][n];
    bf16* dp = dst + (size_t)(n0 + n) * Kp + k0 + kk0;
    *(short8*)dp = *(short8*)buf;
    *(short8*)(dp + 8) = *(short8*)(buf + 8);
  }
}

// ---------------------------------------------------------------- rmsnorm
__global__ __launch_bounds__(256) void rmsnorm_kernel(
    const float* __restrict__ x, const float* __restrict__ w, bf16* __restrict__ out) {
  int t = blockIdx.x;
  const float* xr = x + (size_t)t * DM;
  float4 xv = *(const float4*)(xr + threadIdx.x * 4);
  float ss = xv.x * xv.x + xv.y * xv.y + xv.z * xv.z + xv.w * xv.w;
#pragma unroll
  for (int off = 1; off < 64; off <<= 1) ss += __shfl_xor(ss, off);
  __shared__ float sred[4];
  if ((threadIdx.x & 63) == 0) sred[threadIdx.x >> 6] = ss;
  __syncthreads();
  float scale = rsqrtf((sred[0] + sred[1] + sred[2] + sred[3]) * (1.f / DM) + 1e-6f);
  float4 wv = *(const float4*)(w + threadIdx.x * 4);
  bf4 o;
  o.x = (bf16)(xv.x * scale * wv.x); o.y = (bf16)(xv.y * scale * wv.y);
  o.z = (bf16)(xv.z * scale * wv.z); o.w = (bf16)(xv.w * scale * wv.w);
  ((bf4*)(out + (size_t)t * DM))[threadIdx.x] = o;
}

// -------------------------------------------- rmsnorm + router (moe path)
__global__ __launch_bounds__(256) void rmsnorm_router_kernel(
    const float* __restrict__ x, const float* __restrict__ w, const float* __restrict__ rw,
    bf16* __restrict__ out, float* __restrict__ probs,
    int* __restrict__ tIdx, float* __restrict__ tW) {
  int t = blockIdx.x;
  int tid = threadIdx.x, lane = tid & 63, wv = tid >> 6;
  const float* xr = x + (size_t)t * DM;
  float4 xv = *(const float4*)(xr + tid * 4);
  float ss = xv.x * xv.x + xv.y * xv.y + xv.z * xv.z + xv.w * xv.w;
#pragma unroll
  for (int off = 1; off < 64; off <<= 1) ss += __shfl_xor(ss, off);
  __shared__ float sred[4];
  __shared__ float red[4][8];
  if (lane == 0) sred[wv] = ss;
  __syncthreads();
  float scale = rsqrtf((sred[0] + sred[1] + sred[2] + sred[3]) * (1.f / DM) + 1e-6f);
  float4 wvv = *(const float4*)(w + tid * 4);
  float y[4] = {xv.x * scale * wvv.x, xv.y * scale * wvv.y,
                xv.z * scale * wvv.z, xv.w * scale * wvv.w};
  bf4 o; o.x = (bf16)y[0]; o.y = (bf16)y[1]; o.z = (bf16)y[2]; o.w = (bf16)y[3];
  ((bf4*)(out + (size_t)t * DM))[tid] = o;
  float acc[8] = {0, 0, 0, 0, 0, 0, 0, 0};
#pragma unroll
  for (int dd = 0; dd < 4; ++dd) {
    const float* rwr = rw + (size_t)(tid * 4 + dd) * 8;
#pragma unroll
    for (int e = 0; e < 8; ++e) acc[e] += y[dd] * rwr[e];
  }
#pragma unroll
  for (int e = 0; e < 8; ++e)
#pragma unroll
    for (int off = 1; off < 64; off <<= 1) acc[e] += __shfl_xor(acc[e], off);
  if (lane == 0)
#pragma unroll
    for (int e = 0; e < 8; ++e) red[wv][e] = acc[e];
  __syncthreads();
  if (tid == 0) {
    float lg[8];
#pragma unroll
    for (int e = 0; e < 8; ++e) lg[e] = red[0][e] + red[1][e] + red[2][e] + red[3][e];
    float mx = lg[0];
#pragma unroll
    for (int e = 1; e < 8; ++e) mx = fmaxf(mx, lg[e]);
    float p[8], se = 0.f;
#pragma unroll
    for (int e = 0; e < 8; ++e) { p[e] = __expf(lg[e] - mx); se += p[e]; }
#pragma unroll
    for (int e = 0; e < 8; ++e) { p[e] /= se; probs[t * 8 + e] = p[e]; }
    int i1 = 0;
#pragma unroll
    for (int e = 1; e < 8; ++e) if (p[e] > p[i1]) i1 = e;
    int i2 = (i1 == 0) ? 1 : 0;
#pragma unroll
    for (int e = 0; e < 8; ++e) if (e != i1 && p[e] > p[i2]) i2 = e;
    float s = p[i1] + p[i2];
    tIdx[t * 2] = i1; tIdx[t * 2 + 1] = i2;
    tW[t * 2] = p[i1] / s; tW[t * 2 + 1] = p[i2] / s;
  }
}

// ---------------------------------------------------------------- GEMM
// C(MxN) = A(MxK) @ Bt(NxK)^T ; 128x128 tile, BK=64, 4 waves, 16x16x32 bf16 MFMA
// EPI: 2 = Cf = resid + acc ; 4 = QKV + rope epilogue ;
//      6 = Cf[row] = gateW[row]*acc  (gated store into eo buffer)
template <int EPI, bool MOE>
__global__ __launch_bounds__(256) void gemm_bt(
    const bf16* __restrict__ A, const bf16* __restrict__ Bt,
    int M, int N, int K, int lda, int ldb, long bStrideE,
    float* __restrict__ Cf, int ldc,
    const float* __restrict__ resid,
    const int* __restrict__ neCnt, const float* __restrict__ gateW,
    EpiAux aux) {
  __shared__ __align__(16) bf16 As[128 * 64];
  __shared__ __align__(16) bf16 Bs[128 * 64];
  const int tid = threadIdx.x, lane = tid & 63, wave = tid >> 6;
  int m0, expert = 0, mLimit;
  if constexpr (MOE) {
    int slot0 = blockIdx.x * 128;
    expert = slot0 / CAPT;
    int local0 = slot0 - expert * CAPT;
    int ne = neCnt[expert];
    if (local0 >= ne) return;
    m0 = slot0;
    mLimit = ne - local0;
  } else {
    m0 = blockIdx.x * 128;
    mLimit = M - m0;
  }
  if (mLimit > 128) mLimit = 128;
  const int n0 = blockIdx.y * 128;
  const bf16* Bte = Bt + (MOE ? (long)expert * bStrideE : 0L);

  const bf16* aSrc[4]; const bf16* bSrc[4];
  bf16* aDst[4]; bf16* bDst[4];
#pragma unroll
  for (int it = 0; it < 4; ++it) {
    int c = it * 256 + tid;
    int r = c >> 3, q = c & 7;
    int kq = q ^ (r & 7);
    int rr = r < mLimit ? r : (mLimit - 1);
    aSrc[it] = A + (long)(m0 + rr) * lda + kq * 8;
    int nn = n0 + r; if (nn > N - 1) nn = N - 1;
    bSrc[it] = Bte + (long)nn * ldb + kq * 8;
    aDst[it] = As + (size_t)(it * 256 + wave * 64) * 8;
    bDst[it] = Bs + (size_t)(it * 256 + wave * 64) * 8;
  }

  floatx4 acc[4][4];
#pragma unroll
  for (int i = 0; i < 4; ++i)
#pragma unroll
    for (int j = 0; j < 4; ++j) { floatx4 z = {0.f, 0.f, 0.f, 0.f}; acc[i][j] = z; }

  const int wm = (wave & 1) * 64, wn = (wave >> 1) * 64;
  const int l15 = lane & 15, quad = lane >> 4;
  int aOff[4][2], bOff[4][2];
#pragma unroll
  for (int i = 0; i < 4; ++i) {
    int m = wm + i * 16 + l15;
    int n = wn + i * 16 + l15;
#pragma unroll
    for (int h = 0; h < 2; ++h) {
      aOff[i][h] = (((m << 3) | ((h * 4 + quad) ^ (m & 7))) << 3);
      bOff[i][h] = (((n << 3) | ((h * 4 + quad) ^ (n & 7))) << 3);
    }
  }

  const int kIters = K >> 6;
  for (int kt = 0; kt < kIters; ++kt) {
    __syncthreads();
#pragma unroll
    for (int it = 0; it < 4; ++it) {
      gld16(aSrc[it], aDst[it]);
      gld16(bSrc[it], bDst[it]);
      aSrc[it] += 64; bSrc[it] += 64;
    }
    __syncthreads();
#pragma unroll
    for (int h = 0; h < 2; ++h) {
      short8 af[4], bfr[4];
#pragma unroll
      for (int i = 0; i < 4; ++i) af[i] = *(const short8*)(As + aOff[i][h]);
#pragma unroll
      for (int j = 0; j < 4; ++j) bfr[j] = *(const short8*)(Bs + bOff[j][h]);
#pragma unroll
      for (int i = 0; i < 4; ++i)
#pragma unroll
        for (int j = 0; j < 4; ++j)
          acc[i][j] = __builtin_amdgcn_mfma_f32_16x16x32_bf16(af[i], bfr[j], acc[i][j], 0, 0, 0);
    }
  }

  // epilogue: C row = quad*4+reg, col = lane&15
  if constexpr (EPI == 4) {
#pragma unroll
    for (int i = 0; i < 4; ++i) {
#pragma unroll
      for (int r = 0; r < 4; ++r) {
        int row = wm + i * 16 + quad * 4 + r;
        int t = m0 + row;
        int s = t & (SEQ - 1);
        if (n0 < 1024) {
#pragma unroll
          for (int j = 0; j < 2; ++j) {
            int col = n0 + wn + j * 16 + l15;
            int dlo = col & 63;
            float x1 = acc[i][j][r], x2 = acc[i][j + 2][r];
            float ch = aux.cosb[s * 64 + dlo], sh = aux.sinb[s * 64 + dlo];
            aux.qb[(size_t)t * DM + col]      = (bf16)((x1 * ch - x2 * sh) * 0.125f);
            aux.qb[(size_t)t * DM + col + 32] = (bf16)((x1 * sh + x2 * ch) * 0.125f);
          }
        } else if (n0 < 1280) {
#pragma unroll
          for (int j = 0; j < 2; ++j) {
            int ck = n0 + wn + j * 16 + l15 - 1024;
            int dlo = ck & 63;
            float x1 = acc[i][j][r], x2 = acc[i][j + 2][r];
            float ch = aux.cosb[s * 64 + dlo], sh = aux.sinb[s * 64 + dlo];
            float o1 = x1 * ch - x2 * sh, o2 = x1 * sh + x2 * ch;
            aux.kb[(size_t)t * 256 + ck]        = (bf16)o1;
            aux.kb[(size_t)t * 256 + ck + 32]   = (bf16)o2;
            aux.newk[(size_t)t * 256 + ck]      = o1;
            aux.newk[(size_t)t * 256 + ck + 32] = o2;
          }
        } else {
#pragma unroll
          for (int j = 0; j < 4; ++j) {
            int cv = n0 + wn + j * 16 + l15 - 1280;
            float v = acc[i][j][r];
            aux.vb[(size_t)t * 256 + cv]   = (bf16)v;
            aux.newv[(size_t)t * 256 + cv] = v;
          }
        }
      }
    }
    return;
  }
#pragma unroll
  for (int i = 0; i < 4; ++i) {
#pragma unroll
    for (int j = 0; j < 4; ++j) {
      int col = n0 + wn + j * 16 + l15;
#pragma unroll
      for (int r = 0; r < 4; ++r) {
        int row = wm + i * 16 + quad * 4 + r;
        if (row >= mLimit || col >= N) continue;
        float v = acc[i][j][r];
        if constexpr (EPI == 2) {
          size_t o = (size_t)(m0 + row) * ldc + col;
          Cf[o] = resid[o] + v;
        } else if constexpr (EPI == 6) {
          Cf[(size_t)(m0 + row) * ldc + col] = gateW[m0 + row] * v;
        }
      }
    }
  }
}

// ------------------------------------------------------ dual GEMM + swiglu
// act = silu(A@B1t^T) * (A@B3t^T), written bf16 to actOut (ldc = HIDP)
template <bool GATHER, bool MOE>
__global__ __launch_bounds__(256) void gemm_dual(
    const bf16* __restrict__ A, const bf16* __restrict__ B1t, const bf16* __restrict__ B3t,
    int M, int N, int K, int lda, int ldb, long bStrideE,
    bf16* __restrict__ actOut, int ldc,
    const int* __restrict__ tokList, const int* __restrict__ neCnt) {
  __shared__ __align__(16) bf16 As[128 * 64];
  __shared__ __align__(16) bf16 B1s[128 * 64];
  __shared__ __align__(16) bf16 B3s[128 * 64];
  const int tid = threadIdx.x, lane = tid & 63, wave = tid >> 6;
  int m0, expert = 0, mLimit;
  if constexpr (MOE) {
    int slot0 = blockIdx.x * 128;
    expert = slot0 / CAPT;
    int local0 = slot0 - expert * CAPT;
    int ne = neCnt[expert];
    if (local0 >= ne) return;
    m0 = slot0;
    mLimit = ne - local0;
  } else {
    m0 = blockIdx.x * 128;
    mLimit = M - m0;
  }
  if (mLimit > 128) mLimit = 128;
  const int n0 = blockIdx.y * 128;
  const bf16* B1e = B1t + (MOE ? (long)expert * bStrideE : 0L);
  const bf16* B3e = B3t + (MOE ? (long)expert * bStrideE : 0L);

  const bf16* aSrc[4]; const bf16* b1Src[4]; const bf16* b3Src[4];
  bf16* aDst[4]; bf16* b1Dst[4]; bf16* b3Dst[4];
#pragma unroll
  for (int it = 0; it < 4; ++it) {
    int c = it * 256 + tid;
    int r = c >> 3, q = c & 7;
    int kq = q ^ (r & 7);
    int rr = r < mLimit ? r : (mLimit - 1);
    long arow;
    if constexpr (GATHER) arow = tokList[m0 + rr];
    else arow = (long)(m0 + rr);
    aSrc[it] = A + arow * lda + kq * 8;
    int nn = n0 + r; if (nn > N - 1) nn = N - 1;
    b1Src[it] = B1e + (long)nn * ldb + kq * 8;
    b3Src[it] = B3e + (long)nn * ldb + kq * 8;
    aDst[it]  = As  + (size_t)(it * 256 + wave * 64) * 8;
    b1Dst[it] = B1s + (size_t)(it * 256 + wave * 64) * 8;
    b3Dst[it] = B3s + (size_t)(it * 256 + wave * 64) * 8;
  }

  floatx4 acc1[4][4], acc3[4][4];
#pragma unroll
  for (int i = 0; i < 4; ++i)
#pragma unroll
    for (int j = 0; j < 4; ++j) {
      floatx4 z = {0.f, 0.f, 0.f, 0.f};
      acc1[i][j] = z; acc3[i][j] = z;
    }

  const int wm = (wave & 1) * 64, wn = (wave >> 1) * 64;
  const int l15 = lane & 15, quad = lane >> 4;
  int aOff[4][2], bOff[4][2];
#pragma unroll
  for (int i = 0; i < 4; ++i) {
    int m = wm + i * 16 + l15;
    int n = wn + i * 16 + l15;
#pragma unroll
    for (int h = 0; h < 2; ++h) {
      aOff[i][h] = (((m << 3) | ((h * 4 + quad) ^ (m & 7))) << 3);
      bOff[i][h] = (((n << 3) | ((h * 4 + quad) ^ (n & 7))) << 3);
    }
  }

  const int kIters = K >> 6;
  for (int kt = 0; kt < kIters; ++kt) {
    __syncthreads();
#pragma unroll
    for (int it = 0; it < 4; ++it) {
      gld16(aSrc[it], aDst[it]);
      gld16(b1Src[it], b1Dst[it]);
      gld16(b3Src[it], b3Dst[it]);
      aSrc[it] += 64; b1Src[it] += 64; b3Src[it] += 64;
    }
    __syncthreads();
#pragma unroll
    for (int h = 0; h < 2; ++h) {
      short8 af[4];
#pragma unroll
      for (int i = 0; i < 4; ++i) af[i] = *(const short8*)(As + aOff[i][h]);
#pragma unroll
      for (int j = 0; j < 4; ++j) {
        short8 b1f = *(const short8*)(B1s + bOff[j][h]);
#pragma unroll
        for (int i = 0; i < 4; ++i)
          acc1[i][j] = __builtin_amdgcn_mfma_f32_16x16x32_bf16(af[i], b1f, acc1[i][j], 0, 0, 0);
      }
#pragma unroll
      for (int j = 0; j < 4; ++j) {
        short8 b3f = *(const short8*)(B3s + bOff[j][h]);
#pragma unroll
        for (int i = 0; i < 4; ++i)
          acc3[i][j] = __builtin_amdgcn_mfma_f32_16x16x32_bf16(af[i], b3f, acc3[i][j], 0, 0, 0);
      }
    }
  }

#pragma unroll
  for (int i = 0; i < 4; ++i) {
#pragma unroll
    for (int j = 0; j < 4; ++j) {
      int col = n0 + wn + j * 16 + l15;
#pragma unroll
      for (int r = 0; r < 4; ++r) {
        int row = wm + i * 16 + quad * 4 + r;
        if (row >= mLimit || col >= N) continue;
        float a1 = acc1[i][j][r], a3 = acc3[i][j][r];
        float sl = a1 / (1.f + __expf(-a1));
        actOut[(size_t)(m0 + row) * ldc + col] = (bf16)(sl * a3);
      }
    }
  }
}

// ------------------------------------------- V transpose: vb[t][256] -> vt[bg][d][s]
__global__ __launch_bounds__(256) void vt_kernel(
    const bf16* __restrict__ vb, bf16* __restrict__ vt) {
  __shared__ __align__(16) bf16 tile[64 * 72];
  int t0 = blockIdx.x * 64, bg = blockIdx.y;
  int b = bg >> 2, g = bg & 3;
  int tid = threadIdx.x;
  for (int c = tid; c < 512; c += 256) {
    int r = c >> 3, d8 = (c & 7) * 8;
    *(short8*)(tile + r * 72 + d8) =
        *(const short8*)(vb + (size_t)(b * SEQ + t0 + r) * 256 + g * 64 + d8);
  }
  __syncthreads();
  for (int c = tid; c < 512; c += 256) {
    int d = c >> 3, s8 = (c & 7) * 8;
    bf16 tmp[8];
#pragma unroll
    for (int x = 0; x < 8; ++x) tmp[x] = tile[(s8 + x) * 72 + d];
    *(short8*)(vt + ((size_t)bg * 64 + d) * SEQ + t0 + s8) = *(short8*)tmp;
  }
}

// ---------------------------------------------------------------- flash attention
// Q pre-scaled by 0.125. No-max softmax (|scores| <= ~2 by construction):
// P = exp(S), row-sum via MFMA against all-ones B fragment. Balanced pairing:
// block (i) handles q-tiles i and 31-i => constant 33 K-iters per block.
__global__ __launch_bounds__(256) void attn_kernel(
    const bf16* __restrict__ Q, const bf16* __restrict__ Kc, const bf16* __restrict__ Vt,
    bf16* __restrict__ AO) {
  __shared__ __align__(16) bf16 Qs[64 * 64];
  __shared__ __align__(16) bf16 Ks[64 * 64];
  __shared__ __align__(16) bf16 Vs[64 * 64];   // Vs[d][k]
  __shared__ __align__(16) bf16 Ps[4][16 * 64];
  const int pairI = blockIdx.x, h = blockIdx.y, b = blockIdx.z;
  const int g = h >> 2;
  const int tid = threadIdx.x, lane = tid & 63, wave = tid >> 6;
  const int l15 = lane & 15, quad = lane >> 4;

  // K/V staging bases (kt-advanced by offset)
  const bf16* kSrc[2]; const bf16* vSrc[2]; bf16* kDst[2]; bf16* vDst[2];
#pragma unroll
  for (int it = 0; it < 2; ++it) {
    int c = it * 256 + tid;
    int r = c >> 3, p = c & 7;
    int kq = p ^ (r & 7);
    kSrc[it] = Kc + (size_t)(b * SEQ + r) * 256 + g * 64 + kq * 8;
    vSrc[it] = Vt + ((size_t)(b * 4 + g) * 64 + r) * SEQ + kq * 8;
    kDst[it] = Ks + (size_t)(it * 256 + wave * 64) * 8;
    vDst[it] = Vs + (size_t)(it * 256 + wave * 64) * 8;
  }

  // fragment offsets
  int qOff[2], kvOff[4][2], pOff[2];
#pragma unroll
  for (int hh = 0; hh < 2; ++hh) {
    int m = wave * 16 + l15;
    qOff[hh] = (m << 6) + (((hh * 4 + quad) ^ (m & 7)) << 3);
#pragma unroll
    for (int j = 0; j < 4; ++j) {
      int n = j * 16 + l15;
      kvOff[j][hh] = (n << 6) + (((hh * 4 + quad) ^ (n & 7)) << 3);
    }
    int cblk = (hh * 2 + (quad >> 1)) ^ (l15 >> 2);
    pOff[hh] = (l15 << 6) + (cblk << 4) + ((quad & 1) << 3);
  }
  bf16* pw = &Ps[wave][0];
  const int rowl = wave * 16 + quad * 4;

  // all-ones bf16 B fragment (for row-sum MFMA)
  short8 onesb;
#pragma unroll
  for (int e = 0; e < 8; ++e) onesb[e] = (short)0x3F80;

  for (int ph = 0; ph < 2; ++ph) {
    const int q0 = (ph == 0 ? pairI : 31 - pairI) * 64;
    __syncthreads();   // protect Qs reuse across phases
    // Q staging
#pragma unroll
    for (int it = 0; it < 2; ++it) {
      int c = it * 256 + tid;
      int r = c >> 3, p = c & 7;
      int kq = p ^ (r & 7);
      gld16(Q + (size_t)(b * SEQ + q0 + r) * DM + h * 64 + kq * 8,
            Qs + (size_t)(it * 256 + wave * 64) * 8);
    }

    floatx4 oacc[4], sumacc;
#pragma unroll
    for (int r = 0; r < 4; ++r) { floatx4 z = {0.f, 0.f, 0.f, 0.f}; oacc[r] = z; }
    { floatx4 z = {0.f, 0.f, 0.f, 0.f}; sumacc = z; }

    const int nkt = (q0 >> 6) + 1;
    for (int kt = 0; kt < nkt; ++kt) {
      __syncthreads();   // drains Q/K/V gld16 + prior compute
#pragma unroll
      for (int it = 0; it < 2; ++it) {
        gld16(kSrc[it] + (size_t)kt * 64 * 256, kDst[it]);
        gld16(vSrc[it] + kt * 64, vDst[it]);
      }
      __syncthreads();

      floatx4 sacc[4];
#pragma unroll
      for (int j = 0; j < 4; ++j) { floatx4 z = {0.f, 0.f, 0.f, 0.f}; sacc[j] = z; }
#pragma unroll
      for (int hh = 0; hh < 2; ++hh) {
        short8 aq = *(const short8*)(Qs + qOff[hh]);
#pragma unroll
        for (int j = 0; j < 4; ++j)
          sacc[j] = __builtin_amdgcn_mfma_f32_16x16x32_bf16(
              aq, *(const short8*)(Ks + kvOff[j][hh]), sacc[j], 0, 0, 0);
      }

      const bool lastTile = (kt == nkt - 1);
#pragma unroll
      for (int j = 0; j < 4; ++j) {
        int sw = ((j ^ quad) << 4) + l15;   // conflict-free store swizzle
        int colg = j * 16 + l15;
#pragma unroll
        for (int r = 0; r < 4; ++r) {
          float p = __expf(sacc[j][r]);
          if (lastTile && colg > rowl + r) p = 0.f;
          pw[(quad * 4 + r) * 64 + sw] = (bf16)p;
        }
      }
      asm volatile("s_waitcnt lgkmcnt(0)" ::: "memory");
#pragma unroll
      for (int hh = 0; hh < 2; ++hh) {
        short8 ap = *(const short8*)(pw + pOff[hh]);
#pragma unroll
        for (int j = 0; j < 4; ++j)
          oacc[j] = __builtin_amdgcn_mfma_f32_16x16x32_bf16(
              ap, *(const short8*)(Vs + kvOff[j][hh]), oacc[j], 0, 0, 0);
        sumacc = __builtin_amdgcn_mfma_f32_16x16x32_bf16(ap, onesb, sumacc, 0, 0, 0);
      }
    }

    float inv[4];
#pragma unroll
    for (int r = 0; r < 4; ++r) inv[r] = 1.f / sumacc[r];
#pragma unroll
    for (int j = 0; j < 4; ++j)
#pragma unroll
      for (int r = 0; r < 4; ++r) {
        int t = b * SEQ + q0 + rowl + r;
        AO[(size_t)t * DM + h * 64 + j * 16 + l15] = (bf16)(oacc[j][r] * inv[r]);
      }
  }
}

// ------------------------------------------------- capacity assignment (8 blocks)
__global__ __launch_bounds__(256) void assign_kernel(
    const int* __restrict__ tIdx, const float* __restrict__ tW,
    int* __restrict__ tokList, float* __restrict__ gateW,
    int* __restrict__ neCnt, int* __restrict__ cntFull, int* __restrict__ slotOf) {
  int e = blockIdx.x;
  __shared__ int waveTot[4];
  __shared__ int offs;
  int tid = threadIdx.x, lane = tid & 63, wv = tid >> 6;
  if (tid == 0) offs = 0;
  __syncthreads();
  for (int base = 0; base < TTOK; base += 256) {
    int t = base + tid;
    int a = tIdx[t * 2], b2 = tIdx[t * 2 + 1];
    bool sel = (a == e) || (b2 == e);
    unsigned long long mask = __ballot(sel);
    int wrank = __popcll(mask & ((1ull << lane) - 1ull));
    if (lane == 0) waveTot[wv] = __popcll(mask);
    __syncthreads();
    int pre = offs;
    for (int w2 = 0; w2 < wv; ++w2) pre += waveTot[w2];
    int rank = pre + wrank;
    if (sel && rank < CAPT) {
      int slot = e * CAPT + rank;
      tokList[slot] = t;
      gateW[slot] = (a == e) ? tW[t * 2] : tW[t * 2 + 1];
      slotOf[t * 2 + ((a == e) ? 0 : 1)] = slot;
    }
    __syncthreads();
    if (tid == 0) offs += waveTot[0] + waveTot[1] + waveTot[2] + waveTot[3];
    __syncthreads();
  }
  if (tid == 0) {
    cntFull[e] = offs;
    neCnt[e] = offs < CAPT ? offs : CAPT;
  }
}

// ---------------------------------------------------------------- aux loss / util
__global__ __launch_bounds__(256) void aux_kernel(
    const float* __restrict__ probs, const int* __restrict__ cntFull,
    float* __restrict__ outAux) {
  __shared__ float psum[8];
  if (threadIdx.x < 8) psum[threadIdx.x] = 0.f;
  __syncthreads();
  float lp[8] = {0, 0, 0, 0, 0, 0, 0, 0};
  for (int t = threadIdx.x; t < TTOK; t += 256) {
#pragma unroll
    for (int e = 0; e < 8; ++e) lp[e] += probs[t * 8 + e];
  }
#pragma unroll
  for (int e = 0; e < 8; ++e)
#pragma unroll
    for (int off = 1; off < 64; off <<= 1) lp[e] += __shfl_xor(lp[e], off);
  if ((threadIdx.x & 63) == 0)
#pragma unroll
    for (int e = 0; e < 8; ++e) atomicAdd(&psum[e], lp[e]);
  __syncthreads();
  if (threadIdx.x == 0) {
    float aux = 0.f; int used = 0;
    for (int e = 0; e < 8; ++e) {
      aux += (psum[e] / (float)TTOK) * ((float)cntFull[e] / (float)TTOK);
      if (cntFull[e] > 0) used++;
    }
    outAux[0] = 8.f * aux;
    outAux[1] = 100.f * (float)used / 8.f;
  }
}

// --------------------------------------------- combine: out += gathered eo rows
__global__ __launch_bounds__(256) void combine_kernel(
    float* __restrict__ outp, const float* __restrict__ eo,
    const int* __restrict__ slotOf) {
  int t = blockIdx.x, tid = threadIdx.x;
  float4 v = ((const float4*)(outp + (size_t)t * DM))[tid];
  int s0 = slotOf[t * 2], s1 = slotOf[t * 2 + 1];
  if (s0 >= 0) {
    float4 e = ((const float4*)(eo + (size_t)s0 * DM))[tid];
    v.x += e.x; v.y += e.y; v.z += e.z; v.w += e.w;
  }
  if (s1 >= 0) {
    float4 e = ((const float4*)(eo + (size_t)s1 * DM))[tid];
    v.x += e.x; v.y += e.y; v.z += e.z; v.w += e.w;
  }
  ((float4*)(outp + (size_t)t * DM))[tid] = v;
}

// ---------------------------------------------------------------- launch
extern "C" void kernel_launch(void* const* d_in, const int* in_sizes, int n_in,
                              void* d_out, int out_size, void* d_ws, size_t ws_size,
                              hipStream_t stream) {
  (void)in_sizes; (void)n_in; (void)out_size; (void)ws_size;
  const float* x     = (const float*)d_in[0];
  const float* cosb  = (const float*)d_in[1];
  const float* sinb  = (const float*)d_in[2];
  const float* attnw = (const float*)d_in[4];
  const float* moew  = (const float*)d_in[5];
  const float* wq  = (const float*)d_in[6];
  const float* wk  = (const float*)d_in[7];
  const float* wv  = (const float*)d_in[8];
  const float* wo  = (const float*)d_in[9];
  const float* rw  = (const float*)d_in[10];
  const float* ew1 = (const float*)d_in[11];
  const float* ew2 = (const float*)d_in[12];
  const float* ew3 = (const float*)d_in[13];
  const float* sw1 = (const float*)d_in[14];
  const float* sw2 = (const float*)d_in[15];
  const float* sw3 = (const float*)d_in[16];

  float* outp = (float*)d_out;
  float* auxp = outp + 4194304;
  float* newk = outp + 4194306;
  float* newv = newk + 1048576;

  char* wsp = (char*)d_ws;
  size_t off = 0;
  auto alloc = [&](size_t bytes) -> void* {
    void* p = wsp + off; off += (bytes + 255) & ~(size_t)255; return p;
  };
  bf16* wqkvT = (bf16*)alloc((size_t)1536 * 1024 * 2);
  bf16* woT   = (bf16*)alloc((size_t)1024 * 1024 * 2);
  bf16* sw1T  = (bf16*)alloc((size_t)HIDDEN * 1024 * 2);
  bf16* sw3T  = (bf16*)alloc((size_t)HIDDEN * 1024 * 2);
  bf16* sw2T  = (bf16*)alloc((size_t)1024 * HIDP * 2);
  bf16* ew1T  = (bf16*)alloc((size_t)NEXP * HIDDEN * 1024 * 2);
  bf16* ew3T  = (bf16*)alloc((size_t)NEXP * HIDDEN * 1024 * 2);
  bf16* ew2T  = (bf16*)alloc((size_t)NEXP * 1024 * HIDP * 2);
  bf16* xn    = (bf16*)alloc((size_t)TTOK * DM * 2);
  bf16* qb    = (bf16*)alloc((size_t)TTOK * DM * 2);
  bf16* kb    = (bf16*)alloc((size_t)TTOK * 256 * 2);
  bf16* vb    = (bf16*)alloc((size_t)TTOK * 256 * 2);
  bf16* vt    = (bf16*)alloc((size_t)TTOK * 256 * 2);
  bf16* ao    = (bf16*)alloc((size_t)TTOK * DM * 2);
  float* hbuf = (float*)alloc((size_t)TTOK * DM * 4);
  bf16* hn    = (bf16*)alloc((size_t)TTOK * DM * 2);
  float* probs = (float*)alloc((size_t)TTOK * 8 * 4);
  int*   tIdx  = (int*)alloc((size_t)TTOK * 2 * 4);
  float* tW    = (float*)alloc((size_t)TTOK * 2 * 4);
  int*   tokList = (int*)alloc((size_t)NSLOT * 4);
  float* gateW   = (float*)alloc((size_t)NSLOT * 4);
  int*   neCnt   = (int*)alloc(64);
  int*   cntFull = (int*)alloc(64);
  int*   slotOf  = (int*)alloc((size_t)TTOK * 2 * 4);
  bf16*  mact = (bf16*)alloc((size_t)NSLOT * HIDP * 2);
  float* eo   = (float*)alloc((size_t)NSLOT * DM * 4);

  EpiAux nil{};
  EpiAux ropeAux{cosb, sinb, qb, kb, vb, newk, newv};

  // ---- weight convert + transpose (f32 KxN -> bf16 NxK, zero-pad K to Kp)
  transpose_cvt<<<dim3(16, 16, 1), 256, 0, stream>>>(wq, wqkvT, 1024, 1024, 1024, 0, 0);
  transpose_cvt<<<dim3(4, 16, 1), 256, 0, stream>>>(wk, wqkvT + (size_t)1024 * 1024, 1024, 256, 1024, 0, 0);
  transpose_cvt<<<dim3(4, 16, 1), 256, 0, stream>>>(wv, wqkvT + (size_t)1280 * 1024, 1024, 256, 1024, 0, 0);
  transpose_cvt<<<dim3(16, 16, 1), 256, 0, stream>>>(wo, woT, 1024, 1024, 1024, 0, 0);
  transpose_cvt<<<dim3(22, 16, 1), 256, 0, stream>>>(sw1, sw1T, 1024, HIDDEN, 1024, 0, 0);
  transpose_cvt<<<dim3(22, 16, 1), 256, 0, stream>>>(sw3, sw3T, 1024, HIDDEN, 1024, 0, 0);
  transpose_cvt<<<dim3(16, 22, 1), 256, 0, stream>>>(sw2, sw2T, HIDDEN, 1024, HIDP, 0, 0);
  transpose_cvt<<<dim3(22, 16, NEXP), 256, 0, stream>>>(ew1, ew1T, 1024, HIDDEN, 1024,
      (long)1024 * HIDDEN, (long)HIDDEN * 1024);
  transpose_cvt<<<dim3(22, 16, NEXP), 256, 0, stream>>>(ew3, ew3T, 1024, HIDDEN, 1024,
      (long)1024 * HIDDEN, (long)HIDDEN * 1024);
  transpose_cvt<<<dim3(16, 22, NEXP), 256, 0, stream>>>(ew2, ew2T, HIDDEN, 1024, HIDP,
      (long)HIDDEN * 1024, (long)1024 * HIDP);

  // ---- attention path
  rmsnorm_kernel<<<TTOK, 256, 0, stream>>>(x, attnw, xn);
  gemm_bt<4, false><<<dim3(32, 12), 256, 0, stream>>>(
      xn, wqkvT, TTOK, 1536, 1024, 1024, 1024, 0L,
      nullptr, 0, nullptr, nullptr, nullptr, ropeAux);
  vt_kernel<<<dim3(32, 8), 256, 0, stream>>>(vb, vt);
  attn_kernel<<<dim3(16, NHEAD, 2), 256, 0, stream>>>(qb, kb, vt, ao);
  gemm_bt<2, false><<<dim3(32, 8), 256, 0, stream>>>(
      ao, woT, TTOK, 1024, 1024, 1024, 1024, 0L,
      hbuf, 1024, x, nullptr, nullptr, nil);

  // ---- MoE routing
  rmsnorm_router_kernel<<<TTOK, 256, 0, stream>>>(hbuf, moew, rw, hn, probs, tIdx, tW);
  hipMemsetAsync(slotOf, 0xFF, (size_t)TTOK * 2 * 4, stream);
  assign_kernel<<<NEXP, 256, 0, stream>>>(tIdx, tW, tokList, gateW, neCnt, cntFull, slotOf);
  aux_kernel<<<1, 256, 0, stream>>>(probs, cntFull, auxp);

  // ---- shared expert: out = h + swiglu(hn) @ sw2
  gemm_dual<false, false><<<dim3(32, 11), 256, 0, stream>>>(
      hn, sw1T, sw3T, TTOK, HIDDEN, 1024, 1024, 1024, 0L,
      mact, HIDP, nullptr, nullptr);
  gemm_bt<2, false><<<dim3(32, 8), 256, 0, stream>>>(
      mact, sw2T, TTOK, 1024, HIDP, HIDP, HIDP, 0L,
      outp, 1024, hbuf, nullptr, nullptr, nil);

  // ---- routed experts: gathered dual-GEMM + gated store + combine
  gemm_dual<true, true><<<dim3(NSLOT / 128, 11), 256, 0, stream>>>(
      hn, ew1T, ew3T, NSLOT, HIDDEN, 1024, 1024, 1024, (long)HIDDEN * 1024,
      mact, HIDP, tokList, neCnt);
  gemm_bt<6, true><<<dim3(NSLOT / 128, 8), 256, 0, stream>>>(
      mact, ew2T, NSLOT, 1024, HIDP, HIDP, HIDP, (long)1024 * HIDP,
      eo, 1024, nullptr, neCnt, gateW, nil);
  combine_kernel<<<TTOK, 256, 0, stream>>>(outp, eo, slotOf);
}

// Round 5
// 742.480 us; speedup vs baseline: 1.3373x; 1.0100x over previous
//
#include <hip/hip_runtime.h>
#include <hip/hip_bf16.h>
#include <math.h>

typedef __hip_bfloat16 bf16;
typedef __attribute__((ext_vector_type(8))) short short8;
typedef __attribute__((ext_vector_type(4))) float floatx4;

#define SEQ    2048
#define TTOK   4096
#define DM     1024
#define NHEAD  16
#define NKVH   4
#define HD     64
#define NEXP   8
#define HIDDEN 1365
#define HIDP   1408
#define CAPT   1280
#define NSLOT  (NEXP*CAPT)   /* 10240 */
#define XPE    (CAPT/128)    /* 10 slot-blocks per expert */

// ---------------------------------------------------------------- utilities
__device__ __forceinline__ void gld16(const void* g, void* l) {
  // async global->LDS, 16B per lane; LDS dest = wave-uniform base + lane*16
  __builtin_amdgcn_global_load_lds((const __attribute__((address_space(1))) void*)g,
                                   (__attribute__((address_space(3))) void*)l,
                                   16, 0, 0);
}

struct __align__(8) bf4 { bf16 x, y, z, w; };

struct EpiAux {
  const float* cosb; const float* sinb;
  bf16* qb; bf16* kb; bf16* vb; float* newk; float* newv;
};

// ---------------------------------------------------- weight convert+transpose
// src: (K,N) f32 row-major -> dst: (N,Kp) bf16 row-major, zero-fill k in [K,Kp)
__global__ __launch_bounds__(256) void transpose_cvt(
    const float* __restrict__ src, bf16* __restrict__ dst,
    int K, int N, int Kp, long srcZ, long dstZ) {
  src += (size_t)blockIdx.z * srcZ;
  dst += (size_t)blockIdx.z * dstZ;
  __shared__ float tile[64][65];
  const int tid = threadIdx.x;
  const int k0 = blockIdx.y * 64, n0 = blockIdx.x * 64;
  const int lr = tid >> 4, lc = (tid & 15) * 4;
#pragma unroll
  for (int i = 0; i < 4; ++i) {
    int k = k0 + lr + i * 16;
    int n = n0 + lc;
    float4 v = {0.f, 0.f, 0.f, 0.f};
    if (k < K) {
      if (n + 3 < N) v = *(const float4*)(src + (size_t)k * N + n);
      else {
        float* vp = (float*)&v;
        for (int e = 0; e < 4; ++e) if (n + e < N) vp[e] = src[(size_t)k * N + n + e];
      }
    }
    tile[lr + i * 16][lc] = v.x; tile[lr + i * 16][lc + 1] = v.y;
    tile[lr + i * 16][lc + 2] = v.z; tile[lr + i * 16][lc + 3] = v.w;
  }
  __syncthreads();
  const int n = tid >> 2, kk0 = (tid & 3) * 16;
  if (n0 + n < N) {
    bf16 buf[16];
#pragma unroll
    for (int e = 0; e < 16; ++e) buf[e] = (bf16)tile[kk0 + e][n];
    bf16* dp = dst + (size_t)(n0 + n) * Kp + k0 + kk0;
    *(short8*)dp = *(short8*)buf;
    *(short8*)(dp + 8) = *(short8*)(buf + 8);
  }
}

// ---------------------------------------------------------------- rmsnorm
__global__ __launch_bounds__(256) void rmsnorm_kernel(
    const float* __restrict__ x, const float* __restrict__ w, bf16* __restrict__ out) {
  int t = blockIdx.x;
  const float* xr = x + (size_t)t * DM;
  float4 xv = *(const float4*)(xr + threadIdx.x * 4);
  float ss = xv.x * xv.x + xv.y * xv.y + xv.z * xv.z + xv.w * xv.w;
#pragma unroll
  for (int off = 1; off < 64; off <<= 1) ss += __shfl_xor(ss, off);
  __shared__ float sred[4];
  if ((threadIdx.x & 63) == 0) sred[threadIdx.x >> 6] = ss;
  __syncthreads();
  float scale = rsqrtf((sred[0] + sred[1] + sred[2] + sred[3]) * (1.f / DM) + 1e-6f);
  float4 wv = *(const float4*)(w + threadIdx.x * 4);
  bf4 o;
  o.x = (bf16)(xv.x * scale * wv.x); o.y = (bf16)(xv.y * scale * wv.y);
  o.z = (bf16)(xv.z * scale * wv.z); o.w = (bf16)(xv.w * scale * wv.w);
  ((bf4*)(out + (size_t)t * DM))[threadIdx.x] = o;
}

// -------------------------------------------- rmsnorm + router (moe path)
__global__ __launch_bounds__(256) void rmsnorm_router_kernel(
    const float* __restrict__ x, const float* __restrict__ w, const float* __restrict__ rw,
    bf16* __restrict__ out, float* __restrict__ probs,
    int* __restrict__ tIdx, float* __restrict__ tW) {
  int t = blockIdx.x;
  int tid = threadIdx.x, lane = tid & 63, wv = tid >> 6;
  const float* xr = x + (size_t)t * DM;
  float4 xv = *(const float4*)(xr + tid * 4);
  float ss = xv.x * xv.x + xv.y * xv.y + xv.z * xv.z + xv.w * xv.w;
#pragma unroll
  for (int off = 1; off < 64; off <<= 1) ss += __shfl_xor(ss, off);
  __shared__ float sred[4];
  __shared__ float red[4][8];
  if (lane == 0) sred[wv] = ss;
  __syncthreads();
  float scale = rsqrtf((sred[0] + sred[1] + sred[2] + sred[3]) * (1.f / DM) + 1e-6f);
  float4 wvv = *(const float4*)(w + tid * 4);
  float y[4] = {xv.x * scale * wvv.x, xv.y * scale * wvv.y,
                xv.z * scale * wvv.z, xv.w * scale * wvv.w};
  bf4 o; o.x = (bf16)y[0]; o.y = (bf16)y[1]; o.z = (bf16)y[2]; o.w = (bf16)y[3];
  ((bf4*)(out + (size_t)t * DM))[tid] = o;
  float acc[8] = {0, 0, 0, 0, 0, 0, 0, 0};
#pragma unroll
  for (int dd = 0; dd < 4; ++dd) {
    const float* rwr = rw + (size_t)(tid * 4 + dd) * 8;
#pragma unroll
    for (int e = 0; e < 8; ++e) acc[e] += y[dd] * rwr[e];
  }
#pragma unroll
  for (int e = 0; e < 8; ++e)
#pragma unroll
    for (int off = 1; off < 64; off <<= 1) acc[e] += __shfl_xor(acc[e], off);
  if (lane == 0)
#pragma unroll
    for (int e = 0; e < 8; ++e) red[wv][e] = acc[e];
  __syncthreads();
  if (tid == 0) {
    float lg[8];
#pragma unroll
    for (int e = 0; e < 8; ++e) lg[e] = red[0][e] + red[1][e] + red[2][e] + red[3][e];
    float mx = lg[0];
#pragma unroll
    for (int e = 1; e < 8; ++e) mx = fmaxf(mx, lg[e]);
    float p[8], se = 0.f;
#pragma unroll
    for (int e = 0; e < 8; ++e) { p[e] = __expf(lg[e] - mx); se += p[e]; }
#pragma unroll
    for (int e = 0; e < 8; ++e) { p[e] /= se; probs[t * 8 + e] = p[e]; }
    int i1 = 0;
#pragma unroll
    for (int e = 1; e < 8; ++e) if (p[e] > p[i1]) i1 = e;
    int i2 = (i1 == 0) ? 1 : 0;
#pragma unroll
    for (int e = 0; e < 8; ++e) if (e != i1 && p[e] > p[i2]) i2 = e;
    float s = p[i1] + p[i2];
    tIdx[t * 2] = i1; tIdx[t * 2 + 1] = i2;
    tW[t * 2] = p[i1] / s; tW[t * 2 + 1] = p[i2] / s;
  }
}

// ---------------------------------------------------------------- GEMM
// C(MxN) = A(MxK) @ Bt(NxK)^T ; 128x128 tile, BK=64, 4 waves, 16x16x32 bf16 MFMA
// 1-D grid with XCD-affine swizzle: hw XCD = blockIdx % 8.
//   MOE:  expert = bid&7 (expert pinned to one XCD; A+B stay L2-resident)
//   else: xcd = bid&7 owns xPerXcd M-blocks for all N-tiles (A fetched once)
// EPI: 2 = Cf = resid + acc ; 4 = QKV + rope epilogue ;
//      6 = Cf[row] = gateW[row]*acc  (gated store into eo buffer)
template <int EPI, bool MOE>
__global__ __launch_bounds__(256) void gemm_bt(
    const bf16* __restrict__ A, const bf16* __restrict__ Bt,
    int M, int N, int K, int lda, int ldb, long bStrideE, int xPerXcd,
    float* __restrict__ Cf, int ldc,
    const float* __restrict__ resid,
    const int* __restrict__ neCnt, const float* __restrict__ gateW,
    EpiAux aux) {
  __shared__ __align__(16) bf16 As[128 * 64];
  __shared__ __align__(16) bf16 Bs[128 * 64];
  const int tid = threadIdx.x, lane = tid & 63, wave = tid >> 6;
  const int f = blockIdx.x, lo = f >> 3;
  int m0, n0, expert = 0, mLimit;
  if constexpr (MOE) {
    expert = f & 7;
    int xb = lo % XPE, y = lo / XPE;
    int ne = neCnt[expert];
    if (xb * 128 >= ne) return;
    m0 = expert * CAPT + xb * 128;
    mLimit = ne - xb * 128;
    n0 = y * 128;
  } else {
    int xb = (f & 7) * xPerXcd + lo % xPerXcd;
    n0 = (lo / xPerXcd) * 128;
    m0 = xb * 128;
    mLimit = M - m0;
  }
  if (mLimit > 128) mLimit = 128;
  const bf16* Bte = Bt + (MOE ? (long)expert * bStrideE : 0L);

  const bf16* aSrc[4]; const bf16* bSrc[4];
  bf16* aDst[4]; bf16* bDst[4];
#pragma unroll
  for (int it = 0; it < 4; ++it) {
    int c = it * 256 + tid;
    int r = c >> 3, q = c & 7;
    int kq = q ^ (r & 7);
    int rr = r < mLimit ? r : (mLimit - 1);
    aSrc[it] = A + (long)(m0 + rr) * lda + kq * 8;
    int nn = n0 + r; if (nn > N - 1) nn = N - 1;
    bSrc[it] = Bte + (long)nn * ldb + kq * 8;
    aDst[it] = As + (size_t)(it * 256 + wave * 64) * 8;
    bDst[it] = Bs + (size_t)(it * 256 + wave * 64) * 8;
  }

  floatx4 acc[4][4];
#pragma unroll
  for (int i = 0; i < 4; ++i)
#pragma unroll
    for (int j = 0; j < 4; ++j) { floatx4 z = {0.f, 0.f, 0.f, 0.f}; acc[i][j] = z; }

  const int wm = (wave & 1) * 64, wn = (wave >> 1) * 64;
  const int l15 = lane & 15, quad = lane >> 4;
  int aOff[4][2], bOff[4][2];
#pragma unroll
  for (int i = 0; i < 4; ++i) {
    int m = wm + i * 16 + l15;
    int n = wn + i * 16 + l15;
#pragma unroll
    for (int h = 0; h < 2; ++h) {
      aOff[i][h] = (((m << 3) | ((h * 4 + quad) ^ (m & 7))) << 3);
      bOff[i][h] = (((n << 3) | ((h * 4 + quad) ^ (n & 7))) << 3);
    }
  }

  const int kIters = K >> 6;
  for (int kt = 0; kt < kIters; ++kt) {
    __syncthreads();
#pragma unroll
    for (int it = 0; it < 4; ++it) {
      gld16(aSrc[it], aDst[it]);
      gld16(bSrc[it], bDst[it]);
      aSrc[it] += 64; bSrc[it] += 64;
    }
    __syncthreads();
#pragma unroll
    for (int h = 0; h < 2; ++h) {
      short8 af[4], bfr[4];
#pragma unroll
      for (int i = 0; i < 4; ++i) af[i] = *(const short8*)(As + aOff[i][h]);
#pragma unroll
      for (int j = 0; j < 4; ++j) bfr[j] = *(const short8*)(Bs + bOff[j][h]);
#pragma unroll
      for (int i = 0; i < 4; ++i)
#pragma unroll
        for (int j = 0; j < 4; ++j)
          acc[i][j] = __builtin_amdgcn_mfma_f32_16x16x32_bf16(af[i], bfr[j], acc[i][j], 0, 0, 0);
    }
  }

  // epilogue: C row = quad*4+reg, col = lane&15
  if constexpr (EPI == 4) {
#pragma unroll
    for (int i = 0; i < 4; ++i) {
#pragma unroll
      for (int r = 0; r < 4; ++r) {
        int row = wm + i * 16 + quad * 4 + r;
        int t = m0 + row;
        int s = t & (SEQ - 1);
        if (n0 < 1024) {
#pragma unroll
          for (int j = 0; j < 2; ++j) {
            int col = n0 + wn + j * 16 + l15;
            int dlo = col & 63;
            float x1 = acc[i][j][r], x2 = acc[i][j + 2][r];
            float ch = aux.cosb[s * 64 + dlo], sh = aux.sinb[s * 64 + dlo];
            aux.qb[(size_t)t * DM + col]      = (bf16)((x1 * ch - x2 * sh) * 0.125f);
            aux.qb[(size_t)t * DM + col + 32] = (bf16)((x1 * sh + x2 * ch) * 0.125f);
          }
        } else if (n0 < 1280) {
#pragma unroll
          for (int j = 0; j < 2; ++j) {
            int ck = n0 + wn + j * 16 + l15 - 1024;
            int dlo = ck & 63;
            float x1 = acc[i][j][r], x2 = acc[i][j + 2][r];
            float ch = aux.cosb[s * 64 + dlo], sh = aux.sinb[s * 64 + dlo];
            float o1 = x1 * ch - x2 * sh, o2 = x1 * sh + x2 * ch;
            aux.kb[(size_t)t * 256 + ck]        = (bf16)o1;
            aux.kb[(size_t)t * 256 + ck + 32]   = (bf16)o2;
            aux.newk[(size_t)t * 256 + ck]      = o1;
            aux.newk[(size_t)t * 256 + ck + 32] = o2;
          }
        } else {
#pragma unroll
          for (int j = 0; j < 4; ++j) {
            int cv = n0 + wn + j * 16 + l15 - 1280;
            float v = acc[i][j][r];
            aux.vb[(size_t)t * 256 + cv]   = (bf16)v;
            aux.newv[(size_t)t * 256 + cv] = v;
          }
        }
      }
    }
    return;
  }
#pragma unroll
  for (int i = 0; i < 4; ++i) {
#pragma unroll
    for (int j = 0; j < 4; ++j) {
      int col = n0 + wn + j * 16 + l15;
#pragma unroll
      for (int r = 0; r < 4; ++r) {
        int row = wm + i * 16 + quad * 4 + r;
        if (row >= mLimit || col >= N) continue;
        float v = acc[i][j][r];
        if constexpr (EPI == 2) {
          size_t o = (size_t)(m0 + row) * ldc + col;
          Cf[o] = resid[o] + v;
        } else if constexpr (EPI == 6) {
          Cf[(size_t)(m0 + row) * ldc + col] = gateW[m0 + row] * v;
        }
      }
    }
  }
}

// ------------------------------------------------------ dual GEMM + swiglu
// act = silu(A@B1t^T) * (A@B3t^T), written bf16 to actOut (ldc = HIDP)
// Same XCD-affine 1-D swizzle as gemm_bt.
template <bool GATHER, bool MOE>
__global__ __launch_bounds__(256) void gemm_dual(
    const bf16* __restrict__ A, const bf16* __restrict__ B1t, const bf16* __restrict__ B3t,
    int M, int N, int K, int lda, int ldb, long bStrideE, int xPerXcd,
    bf16* __restrict__ actOut, int ldc,
    const int* __restrict__ tokList, const int* __restrict__ neCnt) {
  __shared__ __align__(16) bf16 As[128 * 64];
  __shared__ __align__(16) bf16 B1s[128 * 64];
  __shared__ __align__(16) bf16 B3s[128 * 64];
  const int tid = threadIdx.x, lane = tid & 63, wave = tid >> 6;
  const int f = blockIdx.x, lo = f >> 3;
  int m0, n0, expert = 0, mLimit;
  if constexpr (MOE) {
    expert = f & 7;
    int xb = lo % XPE, y = lo / XPE;
    int ne = neCnt[expert];
    if (xb * 128 >= ne) return;
    m0 = expert * CAPT + xb * 128;
    mLimit = ne - xb * 128;
    n0 = y * 128;
  } else {
    int xb = (f & 7) * xPerXcd + lo % xPerXcd;
    n0 = (lo / xPerXcd) * 128;
    m0 = xb * 128;
    mLimit = M - m0;
  }
  if (mLimit > 128) mLimit = 128;
  const bf16* B1e = B1t + (MOE ? (long)expert * bStrideE : 0L);
  const bf16* B3e = B3t + (MOE ? (long)expert * bStrideE : 0L);

  const bf16* aSrc[4]; const bf16* b1Src[4]; const bf16* b3Src[4];
  bf16* aDst[4]; bf16* b1Dst[4]; bf16* b3Dst[4];
#pragma unroll
  for (int it = 0; it < 4; ++it) {
    int c = it * 256 + tid;
    int r = c >> 3, q = c & 7;
    int kq = q ^ (r & 7);
    int rr = r < mLimit ? r : (mLimit - 1);
    long arow;
    if constexpr (GATHER) arow = tokList[m0 + rr];
    else arow = (long)(m0 + rr);
    aSrc[it] = A + arow * lda + kq * 8;
    int nn = n0 + r; if (nn > N - 1) nn = N - 1;
    b1Src[it] = B1e + (long)nn * ldb + kq * 8;
    b3Src[it] = B3e + (long)nn * ldb + kq * 8;
    aDst[it]  = As  + (size_t)(it * 256 + wave * 64) * 8;
    b1Dst[it] = B1s + (size_t)(it * 256 + wave * 64) * 8;
    b3Dst[it] = B3s + (size_t)(it * 256 + wave * 64) * 8;
  }

  floatx4 acc1[4][4], acc3[4][4];
#pragma unroll
  for (int i = 0; i < 4; ++i)
#pragma unroll
    for (int j = 0; j < 4; ++j) {
      floatx4 z = {0.f, 0.f, 0.f, 0.f};
      acc1[i][j] = z; acc3[i][j] = z;
    }

  const int wm = (wave & 1) * 64, wn = (wave >> 1) * 64;
  const int l15 = lane & 15, quad = lane >> 4;
  int aOff[4][2], bOff[4][2];
#pragma unroll
  for (int i = 0; i < 4; ++i) {
    int m = wm + i * 16 + l15;
    int n = wn + i * 16 + l15;
#pragma unroll
    for (int h = 0; h < 2; ++h) {
      aOff[i][h] = (((m << 3) | ((h * 4 + quad) ^ (m & 7))) << 3);
      bOff[i][h] = (((n << 3) | ((h * 4 + quad) ^ (n & 7))) << 3);
    }
  }

  const int kIters = K >> 6;
  for (int kt = 0; kt < kIters; ++kt) {
    __syncthreads();
#pragma unroll
    for (int it = 0; it < 4; ++it) {
      gld16(aSrc[it], aDst[it]);
      gld16(b1Src[it], b1Dst[it]);
      gld16(b3Src[it], b3Dst[it]);
      aSrc[it] += 64; b1Src[it] += 64; b3Src[it] += 64;
    }
    __syncthreads();
#pragma unroll
    for (int h = 0; h < 2; ++h) {
      short8 af[4];
#pragma unroll
      for (int i = 0; i < 4; ++i) af[i] = *(const short8*)(As + aOff[i][h]);
#pragma unroll
      for (int j = 0; j < 4; ++j) {
        short8 b1f = *(const short8*)(B1s + bOff[j][h]);
#pragma unroll
        for (int i = 0; i < 4; ++i)
          acc1[i][j] = __builtin_amdgcn_mfma_f32_16x16x32_bf16(af[i], b1f, acc1[i][j], 0, 0, 0);
      }
#pragma unroll
      for (int j = 0; j < 4; ++j) {
        short8 b3f = *(const short8*)(B3s + bOff[j][h]);
#pragma unroll
        for (int i = 0; i < 4; ++i)
          acc3[i][j] = __builtin_amdgcn_mfma_f32_16x16x32_bf16(af[i], b3f, acc3[i][j], 0, 0, 0);
      }
    }
  }

#pragma unroll
  for (int i = 0; i < 4; ++i) {
#pragma unroll
    for (int j = 0; j < 4; ++j) {
      int col = n0 + wn + j * 16 + l15;
#pragma unroll
      for (int r = 0; r < 4; ++r) {
        int row = wm + i * 16 + quad * 4 + r;
        if (row >= mLimit || col >= N) continue;
        float a1 = acc1[i][j][r], a3 = acc3[i][j][r];
        float sl = a1 / (1.f + __expf(-a1));
        actOut[(size_t)(m0 + row) * ldc + col] = (bf16)(sl * a3);
      }
    }
  }
}

// ------------------------------------------- V transpose: vb[t][256] -> vt[bg][d][s]
__global__ __launch_bounds__(256) void vt_kernel(
    const bf16* __restrict__ vb, bf16* __restrict__ vt) {
  __shared__ __align__(16) bf16 tile[64 * 72];
  int t0 = blockIdx.x * 64, bg = blockIdx.y;
  int b = bg >> 2, g = bg & 3;
  int tid = threadIdx.x;
  for (int c = tid; c < 512; c += 256) {
    int r = c >> 3, d8 = (c & 7) * 8;
    *(short8*)(tile + r * 72 + d8) =
        *(const short8*)(vb + (size_t)(b * SEQ + t0 + r) * 256 + g * 64 + d8);
  }
  __syncthreads();
  for (int c = tid; c < 512; c += 256) {
    int d = c >> 3, s8 = (c & 7) * 8;
    bf16 tmp[8];
#pragma unroll
    for (int x = 0; x < 8; ++x) tmp[x] = tile[(s8 + x) * 72 + d];
    *(short8*)(vt + ((size_t)bg * 64 + d) * SEQ + t0 + s8) = *(short8*)tmp;
  }
}

// ---------------------------------------------------------------- flash attention
// Q pre-scaled by 0.125. No-max softmax; row-sum via MFMA vs all-ones.
// Balanced pairing: block i does q-tiles i and 31-i (33 K-iters each).
__global__ __launch_bounds__(256) void attn_kernel(
    const bf16* __restrict__ Q, const bf16* __restrict__ Kc, const bf16* __restrict__ Vt,
    bf16* __restrict__ AO) {
  __shared__ __align__(16) bf16 Qs[64 * 64];
  __shared__ __align__(16) bf16 Ks[64 * 64];
  __shared__ __align__(16) bf16 Vs[64 * 64];   // Vs[d][k]
  __shared__ __align__(16) bf16 Ps[4][16 * 64];
  const int pairI = blockIdx.x, h = blockIdx.y, b = blockIdx.z;
  const int g = h >> 2;
  const int tid = threadIdx.x, lane = tid & 63, wave = tid >> 6;
  const int l15 = lane & 15, quad = lane >> 4;

  const bf16* kSrc[2]; const bf16* vSrc[2]; bf16* kDst[2]; bf16* vDst[2];
#pragma unroll
  for (int it = 0; it < 2; ++it) {
    int c = it * 256 + tid;
    int r = c >> 3, p = c & 7;
    int kq = p ^ (r & 7);
    kSrc[it] = Kc + (size_t)(b * SEQ + r) * 256 + g * 64 + kq * 8;
    vSrc[it] = Vt + ((size_t)(b * 4 + g) * 64 + r) * SEQ + kq * 8;
    kDst[it] = Ks + (size_t)(it * 256 + wave * 64) * 8;
    vDst[it] = Vs + (size_t)(it * 256 + wave * 64) * 8;
  }

  int qOff[2], kvOff[4][2], pOff[2];
#pragma unroll
  for (int hh = 0; hh < 2; ++hh) {
    int m = wave * 16 + l15;
    qOff[hh] = (m << 6) + (((hh * 4 + quad) ^ (m & 7)) << 3);
#pragma unroll
    for (int j = 0; j < 4; ++j) {
      int n = j * 16 + l15;
      kvOff[j][hh] = (n << 6) + (((hh * 4 + quad) ^ (n & 7)) << 3);
    }
    int cblk = (hh * 2 + (quad >> 1)) ^ (l15 >> 2);
    pOff[hh] = (l15 << 6) + (cblk << 4) + ((quad & 1) << 3);
  }
  bf16* pw = &Ps[wave][0];
  const int rowl = wave * 16 + quad * 4;

  short8 onesb;
#pragma unroll
  for (int e = 0; e < 8; ++e) onesb[e] = (short)0x3F80;

  for (int ph = 0; ph < 2; ++ph) {
    const int q0 = (ph == 0 ? pairI : 31 - pairI) * 64;
    __syncthreads();
#pragma unroll
    for (int it = 0; it < 2; ++it) {
      int c = it * 256 + tid;
      int r = c >> 3, p = c & 7;
      int kq = p ^ (r & 7);
      gld16(Q + (size_t)(b * SEQ + q0 + r) * DM + h * 64 + kq * 8,
            Qs + (size_t)(it * 256 + wave * 64) * 8);
    }

    floatx4 oacc[4], sumacc;
#pragma unroll
    for (int r = 0; r < 4; ++r) { floatx4 z = {0.f, 0.f, 0.f, 0.f}; oacc[r] = z; }
    { floatx4 z = {0.f, 0.f, 0.f, 0.f}; sumacc = z; }

    const int nkt = (q0 >> 6) + 1;
    for (int kt = 0; kt < nkt; ++kt) {
      __syncthreads();
#pragma unroll
      for (int it = 0; it < 2; ++it) {
        gld16(kSrc[it] + (size_t)kt * 64 * 256, kDst[it]);
        gld16(vSrc[it] + kt * 64, vDst[it]);
      }
      __syncthreads();

      floatx4 sacc[4];
#pragma unroll
      for (int j = 0; j < 4; ++j) { floatx4 z = {0.f, 0.f, 0.f, 0.f}; sacc[j] = z; }
#pragma unroll
      for (int hh = 0; hh < 2; ++hh) {
        short8 aq = *(const short8*)(Qs + qOff[hh]);
#pragma unroll
        for (int j = 0; j < 4; ++j)
          sacc[j] = __builtin_amdgcn_mfma_f32_16x16x32_bf16(
              aq, *(const short8*)(Ks + kvOff[j][hh]), sacc[j], 0, 0, 0);
      }

      const bool lastTile = (kt == nkt - 1);
#pragma unroll
      for (int j = 0; j < 4; ++j) {
        int sw = ((j ^ quad) << 4) + l15;
        int colg = j * 16 + l15;
#pragma unroll
        for (int r = 0; r < 4; ++r) {
          float p = __expf(sacc[j][r]);
          if (lastTile && colg > rowl + r) p = 0.f;
          pw[(quad * 4 + r) * 64 + sw] = (bf16)p;
        }
      }
      asm volatile("s_waitcnt lgkmcnt(0)" ::: "memory");
#pragma unroll
      for (int hh = 0; hh < 2; ++hh) {
        short8 ap = *(const short8*)(pw + pOff[hh]);
#pragma unroll
        for (int j = 0; j < 4; ++j)
          oacc[j] = __builtin_amdgcn_mfma_f32_16x16x32_bf16(
              ap, *(const short8*)(Vs + kvOff[j][hh]), oacc[j], 0, 0, 0);
        sumacc = __builtin_amdgcn_mfma_f32_16x16x32_bf16(ap, onesb, sumacc, 0, 0, 0);
      }
    }

    float inv[4];
#pragma unroll
    for (int r = 0; r < 4; ++r) inv[r] = 1.f / sumacc[r];
#pragma unroll
    for (int j = 0; j < 4; ++j)
#pragma unroll
      for (int r = 0; r < 4; ++r) {
        int t = b * SEQ + q0 + rowl + r;
        AO[(size_t)t * DM + h * 64 + j * 16 + l15] = (bf16)(oacc[j][r] * inv[r]);
      }
  }
}

// ------------------------------------------------- capacity assignment (8 blocks)
__global__ __launch_bounds__(256) void assign_kernel(
    const int* __restrict__ tIdx, const float* __restrict__ tW,
    int* __restrict__ tokList, float* __restrict__ gateW,
    int* __restrict__ neCnt, int* __restrict__ cntFull, int* __restrict__ slotOf) {
  int e = blockIdx.x;
  __shared__ int waveTot[4];
  __shared__ int offs;
  int tid = threadIdx.x, lane = tid & 63, wv = tid >> 6;
  if (tid == 0) offs = 0;
  __syncthreads();
  for (int base = 0; base < TTOK; base += 256) {
    int t = base + tid;
    int a = tIdx[t * 2], b2 = tIdx[t * 2 + 1];
    bool sel = (a == e) || (b2 == e);
    unsigned long long mask = __ballot(sel);
    int wrank = __popcll(mask & ((1ull << lane) - 1ull));
    if (lane == 0) waveTot[wv] = __popcll(mask);
    __syncthreads();
    int pre = offs;
    for (int w2 = 0; w2 < wv; ++w2) pre += waveTot[w2];
    int rank = pre + wrank;
    if (sel && rank < CAPT) {
      int slot = e * CAPT + rank;
      tokList[slot] = t;
      gateW[slot] = (a == e) ? tW[t * 2] : tW[t * 2 + 1];
      slotOf[t * 2 + ((a == e) ? 0 : 1)] = slot;
    }
    __syncthreads();
    if (tid == 0) offs += waveTot[0] + waveTot[1] + waveTot[2] + waveTot[3];
    __syncthreads();
  }
  if (tid == 0) {
    cntFull[e] = offs;
    neCnt[e] = offs < CAPT ? offs : CAPT;
  }
}

// ---------------------------------------------------------------- aux loss / util
__global__ __launch_bounds__(256) void aux_kernel(
    const float* __restrict__ probs, const int* __restrict__ cntFull,
    float* __restrict__ outAux) {
  __shared__ float psum[8];
  if (threadIdx.x < 8) psum[threadIdx.x] = 0.f;
  __syncthreads();
  float lp[8] = {0, 0, 0, 0, 0, 0, 0, 0};
  for (int t = threadIdx.x; t < TTOK; t += 256) {
#pragma unroll
    for (int e = 0; e < 8; ++e) lp[e] += probs[t * 8 + e];
  }
#pragma unroll
  for (int e = 0; e < 8; ++e)
#pragma unroll
    for (int off = 1; off < 64; off <<= 1) lp[e] += __shfl_xor(lp[e], off);
  if ((threadIdx.x & 63) == 0)
#pragma unroll
    for (int e = 0; e < 8; ++e) atomicAdd(&psum[e], lp[e]);
  __syncthreads();
  if (threadIdx.x == 0) {
    float aux = 0.f; int used = 0;
    for (int e = 0; e < 8; ++e) {
      aux += (psum[e] / (float)TTOK) * ((float)cntFull[e] / (float)TTOK);
      if (cntFull[e] > 0) used++;
    }
    outAux[0] = 8.f * aux;
    outAux[1] = 100.f * (float)used / 8.f;
  }
}

// --------------------------------------------- combine: out += gathered eo rows
__global__ __launch_bounds__(256) void combine_kernel(
    float* __restrict__ outp, const float* __restrict__ eo,
    const int* __restrict__ slotOf) {
  int t = blockIdx.x, tid = threadIdx.x;
  float4 v = ((const float4*)(outp + (size_t)t * DM))[tid];
  int s0 = slotOf[t * 2], s1 = slotOf[t * 2 + 1];
  if (s0 >= 0) {
    float4 e = ((const float4*)(eo + (size_t)s0 * DM))[tid];
    v.x += e.x; v.y += e.y; v.z += e.z; v.w += e.w;
  }
  if (s1 >= 0) {
    float4 e = ((const float4*)(eo + (size_t)s1 * DM))[tid];
    v.x += e.x; v.y += e.y; v.z += e.z; v.w += e.w;
  }
  ((float4*)(outp + (size_t)t * DM))[tid] = v;
}

// ---------------------------------------------------------------- launch
extern "C" void kernel_launch(void* const* d_in, const int* in_sizes, int n_in,
                              void* d_out, int out_size, void* d_ws, size_t ws_size,
                              hipStream_t stream) {
  (void)in_sizes; (void)n_in; (void)out_size; (void)ws_size;
  const float* x     = (const float*)d_in[0];
  const float* cosb  = (const float*)d_in[1];
  const float* sinb  = (const float*)d_in[2];
  const float* attnw = (const float*)d_in[4];
  const float* moew  = (const float*)d_in[5];
  const float* wq  = (const float*)d_in[6];
  const float* wk  = (const float*)d_in[7];
  const float* wv  = (const float*)d_in[8];
  const float* wo  = (const float*)d_in[9];
  const float* rw  = (const float*)d_in[10];
  const float* ew1 = (const float*)d_in[11];
  const float* ew2 = (const float*)d_in[12];
  const float* ew3 = (const float*)d_in[13];
  const float* sw1 = (const float*)d_in[14];
  const float* sw2 = (const float*)d_in[15];
  const float* sw3 = (const float*)d_in[16];

  float* outp = (float*)d_out;
  float* auxp = outp + 4194304;
  float* newk = outp + 4194306;
  float* newv = newk + 1048576;

  char* wsp = (char*)d_ws;
  size_t off = 0;
  auto alloc = [&](size_t bytes) -> void* {
    void* p = wsp + off; off += (bytes + 255) & ~(size_t)255; return p;
  };
  bf16* wqkvT = (bf16*)alloc((size_t)1536 * 1024 * 2);
  bf16* woT   = (bf16*)alloc((size_t)1024 * 1024 * 2);
  bf16* sw1T  = (bf16*)alloc((size_t)HIDDEN * 1024 * 2);
  bf16* sw3T  = (bf16*)alloc((size_t)HIDDEN * 1024 * 2);
  bf16* sw2T  = (bf16*)alloc((size_t)1024 * HIDP * 2);
  bf16* ew1T  = (bf16*)alloc((size_t)NEXP * HIDDEN * 1024 * 2);
  bf16* ew3T  = (bf16*)alloc((size_t)NEXP * HIDDEN * 1024 * 2);
  bf16* ew2T  = (bf16*)alloc((size_t)NEXP * 1024 * HIDP * 2);
  bf16* xn    = (bf16*)alloc((size_t)TTOK * DM * 2);
  bf16* qb    = (bf16*)alloc((size_t)TTOK * DM * 2);
  bf16* kb    = (bf16*)alloc((size_t)TTOK * 256 * 2);
  bf16* vb    = (bf16*)alloc((size_t)TTOK * 256 * 2);
  bf16* vt    = (bf16*)alloc((size_t)TTOK * 256 * 2);
  bf16* ao    = (bf16*)alloc((size_t)TTOK * DM * 2);
  float* hbuf = (float*)alloc((size_t)TTOK * DM * 4);
  bf16* hn    = (bf16*)alloc((size_t)TTOK * DM * 2);
  float* probs = (float*)alloc((size_t)TTOK * 8 * 4);
  int*   tIdx  = (int*)alloc((size_t)TTOK * 2 * 4);
  float* tW    = (float*)alloc((size_t)TTOK * 2 * 4);
  int*   tokList = (int*)alloc((size_t)NSLOT * 4);
  float* gateW   = (float*)alloc((size_t)NSLOT * 4);
  int*   neCnt   = (int*)alloc(64);
  int*   cntFull = (int*)alloc(64);
  int*   slotOf  = (int*)alloc((size_t)TTOK * 2 * 4);
  bf16*  mact = (bf16*)alloc((size_t)NSLOT * HIDP * 2);
  float* eo   = (float*)alloc((size_t)NSLOT * DM * 4);

  EpiAux nil{};
  EpiAux ropeAux{cosb, sinb, qb, kb, vb, newk, newv};

  // ---- weight convert + transpose (f32 KxN -> bf16 NxK, zero-pad K to Kp)
  transpose_cvt<<<dim3(16, 16, 1), 256, 0, stream>>>(wq, wqkvT, 1024, 1024, 1024, 0, 0);
  transpose_cvt<<<dim3(4, 16, 1), 256, 0, stream>>>(wk, wqkvT + (size_t)1024 * 1024, 1024, 256, 1024, 0, 0);
  transpose_cvt<<<dim3(4, 16, 1), 256, 0, stream>>>(wv, wqkvT + (size_t)1280 * 1024, 1024, 256, 1024, 0, 0);
  transpose_cvt<<<dim3(16, 16, 1), 256, 0, stream>>>(wo, woT, 1024, 1024, 1024, 0, 0);
  transpose_cvt<<<dim3(22, 16, 1), 256, 0, stream>>>(sw1, sw1T, 1024, HIDDEN, 1024, 0, 0);
  transpose_cvt<<<dim3(22, 16, 1), 256, 0, stream>>>(sw3, sw3T, 1024, HIDDEN, 1024, 0, 0);
  transpose_cvt<<<dim3(16, 22, 1), 256, 0, stream>>>(sw2, sw2T, HIDDEN, 1024, HIDP, 0, 0);
  transpose_cvt<<<dim3(22, 16, NEXP), 256, 0, stream>>>(ew1, ew1T, 1024, HIDDEN, 1024,
      (long)1024 * HIDDEN, (long)HIDDEN * 1024);
  transpose_cvt<<<dim3(22, 16, NEXP), 256, 0, stream>>>(ew3, ew3T, 1024, HIDDEN, 1024,
      (long)1024 * HIDDEN, (long)HIDDEN * 1024);
  transpose_cvt<<<dim3(16, 22, NEXP), 256, 0, stream>>>(ew2, ew2T, HIDDEN, 1024, HIDP,
      (long)HIDDEN * 1024, (long)1024 * HIDP);

  // ---- attention path
  rmsnorm_kernel<<<TTOK, 256, 0, stream>>>(x, attnw, xn);
  gemm_bt<4, false><<<8 * 4 * 12, 256, 0, stream>>>(
      xn, wqkvT, TTOK, 1536, 1024, 1024, 1024, 0L, 4,
      nullptr, 0, nullptr, nullptr, nullptr, ropeAux);
  vt_kernel<<<dim3(32, 8), 256, 0, stream>>>(vb, vt);
  attn_kernel<<<dim3(16, NHEAD, 2), 256, 0, stream>>>(qb, kb, vt, ao);
  gemm_bt<2, false><<<8 * 4 * 8, 256, 0, stream>>>(
      ao, woT, TTOK, 1024, 1024, 1024, 1024, 0L, 4,
      hbuf, 1024, x, nullptr, nullptr, nil);

  // ---- MoE routing
  rmsnorm_router_kernel<<<TTOK, 256, 0, stream>>>(hbuf, moew, rw, hn, probs, tIdx, tW);
  hipMemsetAsync(slotOf, 0xFF, (size_t)TTOK * 2 * 4, stream);
  assign_kernel<<<NEXP, 256, 0, stream>>>(tIdx, tW, tokList, gateW, neCnt, cntFull, slotOf);
  aux_kernel<<<1, 256, 0, stream>>>(probs, cntFull, auxp);

  // ---- shared expert: out = h + swiglu(hn) @ sw2
  gemm_dual<false, false><<<8 * 4 * 11, 256, 0, stream>>>(
      hn, sw1T, sw3T, TTOK, HIDDEN, 1024, 1024, 1024, 0L, 4,
      mact, HIDP, nullptr, nullptr);
  gemm_bt<2, false><<<8 * 4 * 8, 256, 0, stream>>>(
      mact, sw2T, TTOK, 1024, HIDP, HIDP, HIDP, 0L, 4,
      outp, 1024, hbuf, nullptr, nullptr, nil);

  // ---- routed experts: gathered dual-GEMM + gated store + combine
  gemm_dual<true, true><<<NEXP * XPE * 11, 256, 0, stream>>>(
      hn, ew1T, ew3T, NSLOT, HIDDEN, 1024, 1024, 1024, (long)HIDDEN * 1024, 0,
      mact, HIDP, tokList, neCnt);
  gemm_bt<6, true><<<NEXP * XPE * 8, 256, 0, stream>>>(
      mact, ew2T, NSLOT, 1024, HIDP, HIDP, HIDP, (long)1024 * HIDP, 0,
      eo, 1024, nullptr, neCnt, gateW, nil);
  combine_kernel<<<TTOK, 256, 0, stream>>>(outp, eo, slotOf);
}

// Round 6
// 580.020 us; speedup vs baseline: 1.7119x; 1.2801x over previous
//
#include <hip/hip_runtime.h>
#include <hip/hip_bf16.h>
#include <math.h>

typedef __hip_bfloat16 bf16;
typedef __attribute__((ext_vector_type(8))) short short8;
typedef __attribute__((ext_vector_type(4))) float floatx4;

#define SEQ    2048
#define TTOK   4096
#define DM     1024
#define NHEAD  16
#define NKVH   4
#define HD     64
#define NEXP   8
#define HIDDEN 1365
#define HIDP   1408
#define CAPT   1280
#define NSLOT  (NEXP*CAPT)      /* 10240 routed slots */
#define TSLOT  (NSLOT+TTOK)     /* 14336: + shared-expert identity slots */
#define XPE    (CAPT/128)       /* 10 routed slot-blocks per expert */
#define XBT    14               /* per-XCD M-blocks: 10 routed + 4 shared */

// ---------------------------------------------------------------- utilities
__device__ __forceinline__ void gld16(const void* g, void* l) {
  __builtin_amdgcn_global_load_lds((const __attribute__((address_space(1))) void*)g,
                                   (__attribute__((address_space(3))) void*)l,
                                   16, 0, 0);
}

struct __align__(8) bf4 { bf16 x, y, z, w; };

struct EpiAux {
  const float* cosb; const float* sinb;
  bf16* qb; bf16* kb; bf16* vb; float* newk; float* newv;
};

// ---------------------------------------------------- weight convert+transpose
// src: (K,N) f32 row-major -> dst: (N,Kp) bf16 row-major, zero-fill k in [K,Kp)
__global__ __launch_bounds__(256) void transpose_cvt(
    const float* __restrict__ src, bf16* __restrict__ dst,
    int K, int N, int Kp, long srcZ, long dstZ) {
  src += (size_t)blockIdx.z * srcZ;
  dst += (size_t)blockIdx.z * dstZ;
  __shared__ float tile[64][65];
  const int tid = threadIdx.x;
  const int k0 = blockIdx.y * 64, n0 = blockIdx.x * 64;
  const int lr = tid >> 4, lc = (tid & 15) * 4;
#pragma unroll
  for (int i = 0; i < 4; ++i) {
    int k = k0 + lr + i * 16;
    int n = n0 + lc;
    float4 v = {0.f, 0.f, 0.f, 0.f};
    if (k < K) {
      if (n + 3 < N) v = *(const float4*)(src + (size_t)k * N + n);
      else {
        float* vp = (float*)&v;
        for (int e = 0; e < 4; ++e) if (n + e < N) vp[e] = src[(size_t)k * N + n + e];
      }
    }
    tile[lr + i * 16][lc] = v.x; tile[lr + i * 16][lc + 1] = v.y;
    tile[lr + i * 16][lc + 2] = v.z; tile[lr + i * 16][lc + 3] = v.w;
  }
  __syncthreads();
  const int n = tid >> 2, kk0 = (tid & 3) * 16;
  if (n0 + n < N) {
    bf16 buf[16];
#pragma unroll
    for (int e = 0; e < 16; ++e) buf[e] = (bf16)tile[kk0 + e][n];
    bf16* dp = dst + (size_t)(n0 + n) * Kp + k0 + kk0;
    *(short8*)dp = *(short8*)buf;
    *(short8*)(dp + 8) = *(short8*)(buf + 8);
  }
}

// ---------------------------------------------------------------- rmsnorm
__global__ __launch_bounds__(256) void rmsnorm_kernel(
    const float* __restrict__ x, const float* __restrict__ w, bf16* __restrict__ out) {
  int t = blockIdx.x;
  const float* xr = x + (size_t)t * DM;
  float4 xv = *(const float4*)(xr + threadIdx.x * 4);
  float ss = xv.x * xv.x + xv.y * xv.y + xv.z * xv.z + xv.w * xv.w;
#pragma unroll
  for (int off = 1; off < 64; off <<= 1) ss += __shfl_xor(ss, off);
  __shared__ float sred[4];
  if ((threadIdx.x & 63) == 0) sred[threadIdx.x >> 6] = ss;
  __syncthreads();
  float scale = rsqrtf((sred[0] + sred[1] + sred[2] + sred[3]) * (1.f / DM) + 1e-6f);
  float4 wv = *(const float4*)(w + threadIdx.x * 4);
  bf4 o;
  o.x = (bf16)(xv.x * scale * wv.x); o.y = (bf16)(xv.y * scale * wv.y);
  o.z = (bf16)(xv.z * scale * wv.z); o.w = (bf16)(xv.w * scale * wv.w);
  ((bf4*)(out + (size_t)t * DM))[threadIdx.x] = o;
}

// -------------------------------------------- rmsnorm + router (moe path)
__global__ __launch_bounds__(256) void rmsnorm_router_kernel(
    const float* __restrict__ x, const float* __restrict__ w, const float* __restrict__ rw,
    bf16* __restrict__ out, float* __restrict__ probs,
    int* __restrict__ tIdx, float* __restrict__ tW) {
  int t = blockIdx.x;
  int tid = threadIdx.x, lane = tid & 63, wv = tid >> 6;
  const float* xr = x + (size_t)t * DM;
  float4 xv = *(const float4*)(xr + tid * 4);
  float ss = xv.x * xv.x + xv.y * xv.y + xv.z * xv.z + xv.w * xv.w;
#pragma unroll
  for (int off = 1; off < 64; off <<= 1) ss += __shfl_xor(ss, off);
  __shared__ float sred[4];
  __shared__ float red[4][8];
  if (lane == 0) sred[wv] = ss;
  __syncthreads();
  float scale = rsqrtf((sred[0] + sred[1] + sred[2] + sred[3]) * (1.f / DM) + 1e-6f);
  float4 wvv = *(const float4*)(w + tid * 4);
  float y[4] = {xv.x * scale * wvv.x, xv.y * scale * wvv.y,
                xv.z * scale * wvv.z, xv.w * scale * wvv.w};
  bf4 o; o.x = (bf16)y[0]; o.y = (bf16)y[1]; o.z = (bf16)y[2]; o.w = (bf16)y[3];
  ((bf4*)(out + (size_t)t * DM))[tid] = o;
  float acc[8] = {0, 0, 0, 0, 0, 0, 0, 0};
#pragma unroll
  for (int dd = 0; dd < 4; ++dd) {
    const float* rwr = rw + (size_t)(tid * 4 + dd) * 8;
#pragma unroll
    for (int e = 0; e < 8; ++e) acc[e] += y[dd] * rwr[e];
  }
#pragma unroll
  for (int e = 0; e < 8; ++e)
#pragma unroll
    for (int off = 1; off < 64; off <<= 1) acc[e] += __shfl_xor(acc[e], off);
  if (lane == 0)
#pragma unroll
    for (int e = 0; e < 8; ++e) red[wv][e] = acc[e];
  __syncthreads();
  if (tid == 0) {
    float lg[8];
#pragma unroll
    for (int e = 0; e < 8; ++e) lg[e] = red[0][e] + red[1][e] + red[2][e] + red[3][e];
    float mx = lg[0];
#pragma unroll
    for (int e = 1; e < 8; ++e) mx = fmaxf(mx, lg[e]);
    float p[8], se = 0.f;
#pragma unroll
    for (int e = 0; e < 8; ++e) { p[e] = __expf(lg[e] - mx); se += p[e]; }
#pragma unroll
    for (int e = 0; e < 8; ++e) { p[e] /= se; probs[t * 8 + e] = p[e]; }
    int i1 = 0;
#pragma unroll
    for (int e = 1; e < 8; ++e) if (p[e] > p[i1]) i1 = e;
    int i2 = (i1 == 0) ? 1 : 0;
#pragma unroll
    for (int e = 0; e < 8; ++e) if (e != i1 && p[e] > p[i2]) i2 = e;
    float s = p[i1] + p[i2];
    tIdx[t * 2] = i1; tIdx[t * 2 + 1] = i2;
    tW[t * 2] = p[i1] / s; tW[t * 2 + 1] = p[i2] / s;
  }
}

// ---------------------------------------------------------------- dense GEMM
// 128x128 tile; xcd-affine 1-D grid. EPI: 2 = Cf = resid + acc ; 4 = QKV+rope
template <int EPI>
__global__ __launch_bounds__(256) void gemm_bt(
    const bf16* __restrict__ A, const bf16* __restrict__ Bt,
    int M, int N, int K, int lda, int ldb, int xPerXcd,
    float* __restrict__ Cf, int ldc,
    const float* __restrict__ resid, EpiAux aux) {
  __shared__ __align__(16) bf16 As[128 * 64];
  __shared__ __align__(16) bf16 Bs[128 * 64];
  const int tid = threadIdx.x, lane = tid & 63, wave = tid >> 6;
  const int f = blockIdx.x, lo = f >> 3;
  int xb = (f & 7) * xPerXcd + lo % xPerXcd;
  int n0 = (lo / xPerXcd) * 128;
  int m0 = xb * 128;

  const bf16* aSrc[4]; const bf16* bSrc[4];
  bf16* aDst[4]; bf16* bDst[4];
#pragma unroll
  for (int it = 0; it < 4; ++it) {
    int c = it * 256 + tid;
    int r = c >> 3, q = c & 7;
    int kq = q ^ (r & 7);
    aSrc[it] = A + (long)(m0 + r) * lda + kq * 8;
    bSrc[it] = Bt + (long)(n0 + r) * ldb + kq * 8;
    aDst[it] = As + (size_t)(it * 256 + wave * 64) * 8;
    bDst[it] = Bs + (size_t)(it * 256 + wave * 64) * 8;
  }

  floatx4 acc[4][4];
#pragma unroll
  for (int i = 0; i < 4; ++i)
#pragma unroll
    for (int j = 0; j < 4; ++j) { floatx4 z = {0.f, 0.f, 0.f, 0.f}; acc[i][j] = z; }

  const int wm = (wave & 1) * 64, wn = (wave >> 1) * 64;
  const int l15 = lane & 15, quad = lane >> 4;
  int aOff[4][2], bOff[4][2];
#pragma unroll
  for (int i = 0; i < 4; ++i) {
    int m = wm + i * 16 + l15;
    int n = wn + i * 16 + l15;
#pragma unroll
    for (int h = 0; h < 2; ++h) {
      aOff[i][h] = (((m << 3) | ((h * 4 + quad) ^ (m & 7))) << 3);
      bOff[i][h] = (((n << 3) | ((h * 4 + quad) ^ (n & 7))) << 3);
    }
  }

  const int kIters = K >> 6;
  for (int kt = 0; kt < kIters; ++kt) {
    __syncthreads();
#pragma unroll
    for (int it = 0; it < 4; ++it) {
      gld16(aSrc[it], aDst[it]);
      gld16(bSrc[it], bDst[it]);
      aSrc[it] += 64; bSrc[it] += 64;
    }
    __syncthreads();
#pragma unroll
    for (int h = 0; h < 2; ++h) {
      short8 af[4], bfr[4];
#pragma unroll
      for (int i = 0; i < 4; ++i) af[i] = *(const short8*)(As + aOff[i][h]);
#pragma unroll
      for (int j = 0; j < 4; ++j) bfr[j] = *(const short8*)(Bs + bOff[j][h]);
#pragma unroll
      for (int i = 0; i < 4; ++i)
#pragma unroll
        for (int j = 0; j < 4; ++j)
          acc[i][j] = __builtin_amdgcn_mfma_f32_16x16x32_bf16(af[i], bfr[j], acc[i][j], 0, 0, 0);
    }
  }

  if constexpr (EPI == 4) {
#pragma unroll
    for (int i = 0; i < 4; ++i) {
#pragma unroll
      for (int r = 0; r < 4; ++r) {
        int row = wm + i * 16 + quad * 4 + r;
        int t = m0 + row;
        int s = t & (SEQ - 1);
        if (n0 < 1024) {
#pragma unroll
          for (int j = 0; j < 2; ++j) {
            int col = n0 + wn + j * 16 + l15;
            int dlo = col & 63;
            float x1 = acc[i][j][r], x2 = acc[i][j + 2][r];
            float ch = aux.cosb[s * 64 + dlo], sh = aux.sinb[s * 64 + dlo];
            aux.qb[(size_t)t * DM + col]      = (bf16)((x1 * ch - x2 * sh) * 0.125f);
            aux.qb[(size_t)t * DM + col + 32] = (bf16)((x1 * sh + x2 * ch) * 0.125f);
          }
        } else if (n0 < 1280) {
#pragma unroll
          for (int j = 0; j < 2; ++j) {
            int ck = n0 + wn + j * 16 + l15 - 1024;
            int dlo = ck & 63;
            float x1 = acc[i][j][r], x2 = acc[i][j + 2][r];
            float ch = aux.cosb[s * 64 + dlo], sh = aux.sinb[s * 64 + dlo];
            float o1 = x1 * ch - x2 * sh, o2 = x1 * sh + x2 * ch;
            aux.kb[(size_t)t * 256 + ck]        = (bf16)o1;
            aux.kb[(size_t)t * 256 + ck + 32]   = (bf16)o2;
            aux.newk[(size_t)t * 256 + ck]      = o1;
            aux.newk[(size_t)t * 256 + ck + 32] = o2;
          }
        } else {
#pragma unroll
          for (int j = 0; j < 4; ++j) {
            int cv = n0 + wn + j * 16 + l15 - 1280;
            float v = acc[i][j][r];
            aux.vb[(size_t)t * 256 + cv]   = (bf16)v;
            aux.newv[(size_t)t * 256 + cv] = v;
          }
        }
      }
    }
    return;
  }
#pragma unroll
  for (int i = 0; i < 4; ++i) {
#pragma unroll
    for (int j = 0; j < 4; ++j) {
      int col = n0 + wn + j * 16 + l15;
#pragma unroll
      for (int r = 0; r < 4; ++r) {
        int row = wm + i * 16 + quad * 4 + r;
        size_t o = (size_t)(m0 + row) * ldc + col;
        Cf[o] = resid[o] + acc[i][j][r];
      }
    }
  }
}

// --------------------------------------------------- slot-block decode helper
// f&7 = xcd; lo = f>>3 = xb_local*NY + y ; xb_local<XPE -> routed expert=xcd,
// else shared block (expert 8). Returns false if block has no work.
__device__ __forceinline__ bool slot_block(
    int f, int NY, const int* neCnt, int& expert, int& m0, int& mLimit, int& n0) {
  int xcd = f & 7, lo = f >> 3;
  int xb = lo / NY, y = lo % NY;
  n0 = y * 64;
  if (xb < XPE) {
    expert = xcd;
    int ne = neCnt[xcd];
    if (xb * 128 >= ne) return false;
    m0 = xcd * CAPT + xb * 128;
    mLimit = ne - xb * 128;
    if (mLimit > 128) mLimit = 128;
  } else {
    expert = 8;
    int sb = xcd * 4 + (xb - XPE);
    m0 = NSLOT + sb * 128;
    mLimit = 128;
  }
  return true;
}

// ------------------------------------------------------ MoE dual GEMM + swiglu
// 128x64 tile (acc regs halved -> ~3 waves/SIMD). 9 experts (8 routed + shared).
// mact[slot][col] = silu(hn@ew1^T) * (hn@ew3^T); cols >= HIDDEN zeroed.
__global__ __launch_bounds__(256) void gemm_dual9(
    const bf16* __restrict__ A, const bf16* __restrict__ B1t, const bf16* __restrict__ B3t,
    bf16* __restrict__ mact,
    const int* __restrict__ tokList, const int* __restrict__ neCnt) {
  __shared__ __align__(16) bf16 As[128 * 64];
  __shared__ __align__(16) bf16 B1s[64 * 64];
  __shared__ __align__(16) bf16 B3s[64 * 64];
  const int tid = threadIdx.x, lane = tid & 63, wave = tid >> 6;
  int expert, m0, mLimit, n0;
  if (!slot_block(blockIdx.x, 22, neCnt, expert, m0, mLimit, n0)) return;
  const bf16* B1e = B1t + (long)expert * (HIDDEN * 1024);
  const bf16* B3e = B3t + (long)expert * (HIDDEN * 1024);

  const bf16* aSrc[4]; const bf16* b1Src[2]; const bf16* b3Src[2];
  bf16* aDst[4]; bf16* b1Dst[2]; bf16* b3Dst[2];
#pragma unroll
  for (int it = 0; it < 4; ++it) {
    int c = it * 256 + tid;
    int r = c >> 3, q = c & 7;
    int kq = q ^ (r & 7);
    int rr = r < mLimit ? r : (mLimit - 1);
    aSrc[it] = A + (long)tokList[m0 + rr] * 1024 + kq * 8;
    aDst[it] = As + (size_t)(it * 256 + wave * 64) * 8;
  }
#pragma unroll
  for (int it = 0; it < 2; ++it) {
    int c = it * 256 + tid;
    int r = c >> 3, q = c & 7;
    int kq = q ^ (r & 7);
    int nn = n0 + r; if (nn > HIDDEN - 1) nn = HIDDEN - 1;
    b1Src[it] = B1e + (long)nn * 1024 + kq * 8;
    b3Src[it] = B3e + (long)nn * 1024 + kq * 8;
    b1Dst[it] = B1s + (size_t)(it * 256 + wave * 64) * 8;
    b3Dst[it] = B3s + (size_t)(it * 256 + wave * 64) * 8;
  }

  floatx4 acc1[4][2], acc3[4][2];
#pragma unroll
  for (int i = 0; i < 4; ++i)
#pragma unroll
    for (int j = 0; j < 2; ++j) {
      floatx4 z = {0.f, 0.f, 0.f, 0.f};
      acc1[i][j] = z; acc3[i][j] = z;
    }

  const int wm = (wave & 1) * 64, wn = (wave >> 1) * 32;
  const int l15 = lane & 15, quad = lane >> 4;
  int aOff[4][2], bOff[2][2];
#pragma unroll
  for (int h = 0; h < 2; ++h) {
#pragma unroll
    for (int i = 0; i < 4; ++i) {
      int m = wm + i * 16 + l15;
      aOff[i][h] = (((m << 3) | ((h * 4 + quad) ^ (m & 7))) << 3);
    }
#pragma unroll
    for (int j = 0; j < 2; ++j) {
      int n = wn + j * 16 + l15;
      bOff[j][h] = (((n << 3) | ((h * 4 + quad) ^ (n & 7))) << 3);
    }
  }

  for (int kt = 0; kt < 16; ++kt) {
    __syncthreads();
#pragma unroll
    for (int it = 0; it < 4; ++it) { gld16(aSrc[it], aDst[it]); aSrc[it] += 64; }
#pragma unroll
    for (int it = 0; it < 2; ++it) {
      gld16(b1Src[it], b1Dst[it]); b1Src[it] += 64;
      gld16(b3Src[it], b3Dst[it]); b3Src[it] += 64;
    }
    __syncthreads();
#pragma unroll
    for (int h = 0; h < 2; ++h) {
      short8 af[4];
#pragma unroll
      for (int i = 0; i < 4; ++i) af[i] = *(const short8*)(As + aOff[i][h]);
#pragma unroll
      for (int j = 0; j < 2; ++j) {
        short8 b1f = *(const short8*)(B1s + bOff[j][h]);
        short8 b3f = *(const short8*)(B3s + bOff[j][h]);
#pragma unroll
        for (int i = 0; i < 4; ++i) {
          acc1[i][j] = __builtin_amdgcn_mfma_f32_16x16x32_bf16(af[i], b1f, acc1[i][j], 0, 0, 0);
          acc3[i][j] = __builtin_amdgcn_mfma_f32_16x16x32_bf16(af[i], b3f, acc3[i][j], 0, 0, 0);
        }
      }
    }
  }

#pragma unroll
  for (int i = 0; i < 4; ++i) {
#pragma unroll
    for (int j = 0; j < 2; ++j) {
      int col = n0 + wn + j * 16 + l15;
#pragma unroll
      for (int r = 0; r < 4; ++r) {
        int row = wm + i * 16 + quad * 4 + r;
        if (row >= mLimit) continue;
        float a1 = acc1[i][j][r], a3 = acc3[i][j][r];
        float sl = a1 / (1.f + __expf(-a1));
        mact[(size_t)(m0 + row) * HIDP + col] = (col < HIDDEN) ? (bf16)(sl * a3) : (bf16)0.f;
      }
    }
  }
}

// ------------------------------------------------------ MoE down GEMM (gated)
// 128x64 tile; A = mact slots (no gather); eo[slot] = gateW[slot] * (A@ew2^T)
__global__ __launch_bounds__(256) void gemm_down9(
    const bf16* __restrict__ A, const bf16* __restrict__ B2t,
    bf16* __restrict__ eo,
    const float* __restrict__ gateW, const int* __restrict__ neCnt) {
  __shared__ __align__(16) bf16 As[128 * 64];
  __shared__ __align__(16) bf16 Bs[64 * 64];
  const int tid = threadIdx.x, lane = tid & 63, wave = tid >> 6;
  int expert, m0, mLimit, n0;
  if (!slot_block(blockIdx.x, 16, neCnt, expert, m0, mLimit, n0)) return;
  const bf16* Be = B2t + (long)expert * (1024 * HIDP);

  const bf16* aSrc[4]; const bf16* bSrc[2];
  bf16* aDst[4]; bf16* bDst[2];
#pragma unroll
  for (int it = 0; it < 4; ++it) {
    int c = it * 256 + tid;
    int r = c >> 3, q = c & 7;
    int kq = q ^ (r & 7);
    int rr = r < mLimit ? r : (mLimit - 1);
    aSrc[it] = A + (long)(m0 + rr) * HIDP + kq * 8;
    aDst[it] = As + (size_t)(it * 256 + wave * 64) * 8;
  }
#pragma unroll
  for (int it = 0; it < 2; ++it) {
    int c = it * 256 + tid;
    int r = c >> 3, q = c & 7;
    int kq = q ^ (r & 7);
    bSrc[it] = Be + (long)(n0 + r) * HIDP + kq * 8;
    bDst[it] = Bs + (size_t)(it * 256 + wave * 64) * 8;
  }

  floatx4 acc[4][2];
#pragma unroll
  for (int i = 0; i < 4; ++i)
#pragma unroll
    for (int j = 0; j < 2; ++j) { floatx4 z = {0.f, 0.f, 0.f, 0.f}; acc[i][j] = z; }

  const int wm = (wave & 1) * 64, wn = (wave >> 1) * 32;
  const int l15 = lane & 15, quad = lane >> 4;
  int aOff[4][2], bOff[2][2];
#pragma unroll
  for (int h = 0; h < 2; ++h) {
#pragma unroll
    for (int i = 0; i < 4; ++i) {
      int m = wm + i * 16 + l15;
      aOff[i][h] = (((m << 3) | ((h * 4 + quad) ^ (m & 7))) << 3);
    }
#pragma unroll
    for (int j = 0; j < 2; ++j) {
      int n = wn + j * 16 + l15;
      bOff[j][h] = (((n << 3) | ((h * 4 + quad) ^ (n & 7))) << 3);
    }
  }

  for (int kt = 0; kt < 22; ++kt) {
    __syncthreads();
#pragma unroll
    for (int it = 0; it < 4; ++it) { gld16(aSrc[it], aDst[it]); aSrc[it] += 64; }
#pragma unroll
    for (int it = 0; it < 2; ++it) { gld16(bSrc[it], bDst[it]); bSrc[it] += 64; }
    __syncthreads();
#pragma unroll
    for (int h = 0; h < 2; ++h) {
      short8 af[4];
#pragma unroll
      for (int i = 0; i < 4; ++i) af[i] = *(const short8*)(As + aOff[i][h]);
#pragma unroll
      for (int j = 0; j < 2; ++j) {
        short8 bf = *(const short8*)(Bs + bOff[j][h]);
#pragma unroll
        for (int i = 0; i < 4; ++i)
          acc[i][j] = __builtin_amdgcn_mfma_f32_16x16x32_bf16(af[i], bf, acc[i][j], 0, 0, 0);
      }
    }
  }

#pragma unroll
  for (int i = 0; i < 4; ++i) {
#pragma unroll
    for (int j = 0; j < 2; ++j) {
      int col = n0 + wn + j * 16 + l15;
#pragma unroll
      for (int r = 0; r < 4; ++r) {
        int row = wm + i * 16 + quad * 4 + r;
        if (row >= mLimit) continue;
        eo[(size_t)(m0 + row) * 1024 + col] = (bf16)(gateW[m0 + row] * acc[i][j][r]);
      }
    }
  }
}

// ------------------------------------------- V transpose: vb[t][256] -> vt[bg][d][s]
__global__ __launch_bounds__(256) void vt_kernel(
    const bf16* __restrict__ vb, bf16* __restrict__ vt) {
  __shared__ __align__(16) bf16 tile[64 * 72];
  int t0 = blockIdx.x * 64, bg = blockIdx.y;
  int b = bg >> 2, g = bg & 3;
  int tid = threadIdx.x;
  for (int c = tid; c < 512; c += 256) {
    int r = c >> 3, d8 = (c & 7) * 8;
    *(short8*)(tile + r * 72 + d8) =
        *(const short8*)(vb + (size_t)(b * SEQ + t0 + r) * 256 + g * 64 + d8);
  }
  __syncthreads();
  for (int c = tid; c < 512; c += 256) {
    int d = c >> 3, s8 = (c & 7) * 8;
    bf16 tmp[8];
#pragma unroll
    for (int x = 0; x < 8; ++x) tmp[x] = tile[(s8 + x) * 72 + d];
    *(short8*)(vt + ((size_t)bg * 64 + d) * SEQ + t0 + s8) = *(short8*)tmp;
  }
}

// ---------------------------------------------------------------- flash attention
__global__ __launch_bounds__(256) void attn_kernel(
    const bf16* __restrict__ Q, const bf16* __restrict__ Kc, const bf16* __restrict__ Vt,
    bf16* __restrict__ AO) {
  __shared__ __align__(16) bf16 Qs[64 * 64];
  __shared__ __align__(16) bf16 Ks[64 * 64];
  __shared__ __align__(16) bf16 Vs[64 * 64];
  __shared__ __align__(16) bf16 Ps[4][16 * 64];
  const int pairI = blockIdx.x, h = blockIdx.y, b = blockIdx.z;
  const int g = h >> 2;
  const int tid = threadIdx.x, lane = tid & 63, wave = tid >> 6;
  const int l15 = lane & 15, quad = lane >> 4;

  const bf16* kSrc[2]; const bf16* vSrc[2]; bf16* kDst[2]; bf16* vDst[2];
#pragma unroll
  for (int it = 0; it < 2; ++it) {
    int c = it * 256 + tid;
    int r = c >> 3, p = c & 7;
    int kq = p ^ (r & 7);
    kSrc[it] = Kc + (size_t)(b * SEQ + r) * 256 + g * 64 + kq * 8;
    vSrc[it] = Vt + ((size_t)(b * 4 + g) * 64 + r) * SEQ + kq * 8;
    kDst[it] = Ks + (size_t)(it * 256 + wave * 64) * 8;
    vDst[it] = Vs + (size_t)(it * 256 + wave * 64) * 8;
  }

  int qOff[2], kvOff[4][2], pOff[2];
#pragma unroll
  for (int hh = 0; hh < 2; ++hh) {
    int m = wave * 16 + l15;
    qOff[hh] = (m << 6) + (((hh * 4 + quad) ^ (m & 7)) << 3);
#pragma unroll
    for (int j = 0; j < 4; ++j) {
      int n = j * 16 + l15;
      kvOff[j][hh] = (n << 6) + (((hh * 4 + quad) ^ (n & 7)) << 3);
    }
    int cblk = (hh * 2 + (quad >> 1)) ^ (l15 >> 2);
    pOff[hh] = (l15 << 6) + (cblk << 4) + ((quad & 1) << 3);
  }
  bf16* pw = &Ps[wave][0];
  const int rowl = wave * 16 + quad * 4;

  short8 onesb;
#pragma unroll
  for (int e = 0; e < 8; ++e) onesb[e] = (short)0x3F80;

  for (int ph = 0; ph < 2; ++ph) {
    const int q0 = (ph == 0 ? pairI : 31 - pairI) * 64;
    __syncthreads();
#pragma unroll
    for (int it = 0; it < 2; ++it) {
      int c = it * 256 + tid;
      int r = c >> 3, p = c & 7;
      int kq = p ^ (r & 7);
      gld16(Q + (size_t)(b * SEQ + q0 + r) * DM + h * 64 + kq * 8,
            Qs + (size_t)(it * 256 + wave * 64) * 8);
    }

    floatx4 oacc[4], sumacc;
#pragma unroll
    for (int r = 0; r < 4; ++r) { floatx4 z = {0.f, 0.f, 0.f, 0.f}; oacc[r] = z; }
    { floatx4 z = {0.f, 0.f, 0.f, 0.f}; sumacc = z; }

    const int nkt = (q0 >> 6) + 1;
    for (int kt = 0; kt < nkt; ++kt) {
      __syncthreads();
#pragma unroll
      for (int it = 0; it < 2; ++it) {
        gld16(kSrc[it] + (size_t)kt * 64 * 256, kDst[it]);
        gld16(vSrc[it] + kt * 64, vDst[it]);
      }
      __syncthreads();

      floatx4 sacc[4];
#pragma unroll
      for (int j = 0; j < 4; ++j) { floatx4 z = {0.f, 0.f, 0.f, 0.f}; sacc[j] = z; }
#pragma unroll
      for (int hh = 0; hh < 2; ++hh) {
        short8 aq = *(const short8*)(Qs + qOff[hh]);
#pragma unroll
        for (int j = 0; j < 4; ++j)
          sacc[j] = __builtin_amdgcn_mfma_f32_16x16x32_bf16(
              aq, *(const short8*)(Ks + kvOff[j][hh]), sacc[j], 0, 0, 0);
      }

      const bool lastTile = (kt == nkt - 1);
#pragma unroll
      for (int j = 0; j < 4; ++j) {
        int sw = ((j ^ quad) << 4) + l15;
        int colg = j * 16 + l15;
#pragma unroll
        for (int r = 0; r < 4; ++r) {
          float p = __expf(sacc[j][r]);
          if (lastTile && colg > rowl + r) p = 0.f;
          pw[(quad * 4 + r) * 64 + sw] = (bf16)p;
        }
      }
      asm volatile("s_waitcnt lgkmcnt(0)" ::: "memory");
#pragma unroll
      for (int hh = 0; hh < 2; ++hh) {
        short8 ap = *(const short8*)(pw + pOff[hh]);
#pragma unroll
        for (int j = 0; j < 4; ++j)
          oacc[j] = __builtin_amdgcn_mfma_f32_16x16x32_bf16(
              ap, *(const short8*)(Vs + kvOff[j][hh]), oacc[j], 0, 0, 0);
        sumacc = __builtin_amdgcn_mfma_f32_16x16x32_bf16(ap, onesb, sumacc, 0, 0, 0);
      }
    }

    float inv[4];
#pragma unroll
    for (int r = 0; r < 4; ++r) inv[r] = 1.f / sumacc[r];
#pragma unroll
    for (int j = 0; j < 4; ++j)
#pragma unroll
      for (int r = 0; r < 4; ++r) {
        int t = b * SEQ + q0 + rowl + r;
        AO[(size_t)t * DM + h * 64 + j * 16 + l15] = (bf16)(oacc[j][r] * inv[r]);
      }
  }
}

// ------------------------------------------------- capacity assignment (9 blocks)
// blocks 0..7: per-expert compaction; block 8: identity fill for shared slots
__global__ __launch_bounds__(256) void assign_kernel(
    const int* __restrict__ tIdx, const float* __restrict__ tW,
    int* __restrict__ tokList, float* __restrict__ gateW,
    int* __restrict__ neCnt, int* __restrict__ cntFull, int* __restrict__ slotOf) {
  int e = blockIdx.x;
  int tid = threadIdx.x, lane = tid & 63, wv = tid >> 6;
  if (e == 8) {
    for (int t = tid; t < TTOK; t += 256) {
      tokList[NSLOT + t] = t;
      gateW[NSLOT + t] = 1.0f;
    }
    if (tid == 0) neCnt[8] = TTOK;
    return;
  }
  __shared__ int waveTot[4];
  __shared__ int offs;
  if (tid == 0) offs = 0;
  __syncthreads();
  for (int base = 0; base < TTOK; base += 256) {
    int t = base + tid;
    int a = tIdx[t * 2], b2 = tIdx[t * 2 + 1];
    bool sel = (a == e) || (b2 == e);
    unsigned long long mask = __ballot(sel);
    int wrank = __popcll(mask & ((1ull << lane) - 1ull));
    if (lane == 0) waveTot[wv] = __popcll(mask);
    __syncthreads();
    int pre = offs;
    for (int w2 = 0; w2 < wv; ++w2) pre += waveTot[w2];
    int rank = pre + wrank;
    if (sel && rank < CAPT) {
      int slot = e * CAPT + rank;
      tokList[slot] = t;
      gateW[slot] = (a == e) ? tW[t * 2] : tW[t * 2 + 1];
      slotOf[t * 2 + ((a == e) ? 0 : 1)] = slot;
    }
    __syncthreads();
    if (tid == 0) offs += waveTot[0] + waveTot[1] + waveTot[2] + waveTot[3];
    __syncthreads();
  }
  if (tid == 0) {
    cntFull[e] = offs;
    neCnt[e] = offs < CAPT ? offs : CAPT;
  }
}

// ---------------------------------------------------------------- aux loss / util
__global__ __launch_bounds__(256) void aux_kernel(
    const float* __restrict__ probs, const int* __restrict__ cntFull,
    float* __restrict__ outAux) {
  __shared__ float psum[8];
  if (threadIdx.x < 8) psum[threadIdx.x] = 0.f;
  __syncthreads();
  float lp[8] = {0, 0, 0, 0, 0, 0, 0, 0};
  for (int t = threadIdx.x; t < TTOK; t += 256) {
#pragma unroll
    for (int e = 0; e < 8; ++e) lp[e] += probs[t * 8 + e];
  }
#pragma unroll
  for (int e = 0; e < 8; ++e)
#pragma unroll
    for (int off = 1; off < 64; off <<= 1) lp[e] += __shfl_xor(lp[e], off);
  if ((threadIdx.x & 63) == 0)
#pragma unroll
    for (int e = 0; e < 8; ++e) atomicAdd(&psum[e], lp[e]);
  __syncthreads();
  if (threadIdx.x == 0) {
    float aux = 0.f; int used = 0;
    for (int e = 0; e < 8; ++e) {
      aux += (psum[e] / (float)TTOK) * ((float)cntFull[e] / (float)TTOK);
      if (cntFull[e] > 0) used++;
    }
    outAux[0] = 8.f * aux;
    outAux[1] = 100.f * (float)used / 8.f;
  }
}

// ------------------------- combine: out = hbuf + shared eo + <=2 gated eo rows
__global__ __launch_bounds__(256) void combine_kernel(
    float* __restrict__ outp, const float* __restrict__ hbuf,
    const bf16* __restrict__ eo, const int* __restrict__ slotOf) {
  int t = blockIdx.x, tid = threadIdx.x;
  float4 v = ((const float4*)(hbuf + (size_t)t * DM))[tid];
  bf4 sh = ((const bf4*)(eo + (size_t)(NSLOT + t) * DM))[tid];
  v.x += (float)sh.x; v.y += (float)sh.y; v.z += (float)sh.z; v.w += (float)sh.w;
  int s0 = slotOf[t * 2], s1 = slotOf[t * 2 + 1];
  if (s0 >= 0) {
    bf4 e = ((const bf4*)(eo + (size_t)s0 * DM))[tid];
    v.x += (float)e.x; v.y += (float)e.y; v.z += (float)e.z; v.w += (float)e.w;
  }
  if (s1 >= 0) {
    bf4 e = ((const bf4*)(eo + (size_t)s1 * DM))[tid];
    v.x += (float)e.x; v.y += (float)e.y; v.z += (float)e.z; v.w += (float)e.w;
  }
  ((float4*)(outp + (size_t)t * DM))[tid] = v;
}

// ---------------------------------------------------------------- launch
extern "C" void kernel_launch(void* const* d_in, const int* in_sizes, int n_in,
                              void* d_out, int out_size, void* d_ws, size_t ws_size,
                              hipStream_t stream) {
  (void)in_sizes; (void)n_in; (void)out_size; (void)ws_size;
  const float* x     = (const float*)d_in[0];
  const float* cosb  = (const float*)d_in[1];
  const float* sinb  = (const float*)d_in[2];
  const float* attnw = (const float*)d_in[4];
  const float* moew  = (const float*)d_in[5];
  const float* wq  = (const float*)d_in[6];
  const float* wk  = (const float*)d_in[7];
  const float* wv  = (const float*)d_in[8];
  const float* wo  = (const float*)d_in[9];
  const float* rw  = (const float*)d_in[10];
  const float* ew1 = (const float*)d_in[11];
  const float* ew2 = (const float*)d_in[12];
  const float* ew3 = (const float*)d_in[13];
  const float* sw1 = (const float*)d_in[14];
  const float* sw2 = (const float*)d_in[15];
  const float* sw3 = (const float*)d_in[16];

  float* outp = (float*)d_out;
  float* auxp = outp + 4194304;
  float* newk = outp + 4194306;
  float* newv = newk + 1048576;

  char* wsp = (char*)d_ws;
  size_t off = 0;
  auto alloc = [&](size_t bytes) -> void* {
    void* p = wsp + off; off += (bytes + 255) & ~(size_t)255; return p;
  };
  bf16* wqkvT = (bf16*)alloc((size_t)1536 * 1024 * 2);
  bf16* woT   = (bf16*)alloc((size_t)1024 * 1024 * 2);
  bf16* ew1T  = (bf16*)alloc((size_t)9 * HIDDEN * 1024 * 2);   // slice 8 = sw1
  bf16* ew3T  = (bf16*)alloc((size_t)9 * HIDDEN * 1024 * 2);   // slice 8 = sw3
  bf16* ew2T  = (bf16*)alloc((size_t)9 * 1024 * HIDP * 2);     // slice 8 = sw2
  bf16* xn    = (bf16*)alloc((size_t)TTOK * DM * 2);
  bf16* qb    = (bf16*)alloc((size_t)TTOK * DM * 2);
  bf16* kb    = (bf16*)alloc((size_t)TTOK * 256 * 2);
  bf16* vb    = (bf16*)alloc((size_t)TTOK * 256 * 2);
  bf16* vt    = (bf16*)alloc((size_t)TTOK * 256 * 2);
  bf16* ao    = (bf16*)alloc((size_t)TTOK * DM * 2);
  float* hbuf = (float*)alloc((size_t)TTOK * DM * 4);
  bf16* hn    = (bf16*)alloc((size_t)TTOK * DM * 2);
  float* probs = (float*)alloc((size_t)TTOK * 8 * 4);
  int*   tIdx  = (int*)alloc((size_t)TTOK * 2 * 4);
  float* tW    = (float*)alloc((size_t)TTOK * 2 * 4);
  int*   tokList = (int*)alloc((size_t)TSLOT * 4);
  float* gateW   = (float*)alloc((size_t)TSLOT * 4);
  int*   neCnt   = (int*)alloc(64);
  int*   cntFull = (int*)alloc(64);
  int*   slotOf  = (int*)alloc((size_t)TTOK * 2 * 4);
  bf16*  mact = (bf16*)alloc((size_t)TSLOT * HIDP * 2);
  bf16*  eo   = (bf16*)alloc((size_t)TSLOT * DM * 2);

  EpiAux nil{};
  EpiAux ropeAux{cosb, sinb, qb, kb, vb, newk, newv};

  // ---- weight convert + transpose
  transpose_cvt<<<dim3(16, 16, 1), 256, 0, stream>>>(wq, wqkvT, 1024, 1024, 1024, 0, 0);
  transpose_cvt<<<dim3(4, 16, 1), 256, 0, stream>>>(wk, wqkvT + (size_t)1024 * 1024, 1024, 256, 1024, 0, 0);
  transpose_cvt<<<dim3(4, 16, 1), 256, 0, stream>>>(wv, wqkvT + (size_t)1280 * 1024, 1024, 256, 1024, 0, 0);
  transpose_cvt<<<dim3(16, 16, 1), 256, 0, stream>>>(wo, woT, 1024, 1024, 1024, 0, 0);
  transpose_cvt<<<dim3(22, 16, NEXP), 256, 0, stream>>>(ew1, ew1T, 1024, HIDDEN, 1024,
      (long)1024 * HIDDEN, (long)HIDDEN * 1024);
  transpose_cvt<<<dim3(22, 16, NEXP), 256, 0, stream>>>(ew3, ew3T, 1024, HIDDEN, 1024,
      (long)1024 * HIDDEN, (long)HIDDEN * 1024);
  transpose_cvt<<<dim3(16, 22, NEXP), 256, 0, stream>>>(ew2, ew2T, HIDDEN, 1024, HIDP,
      (long)HIDDEN * 1024, (long)1024 * HIDP);
  transpose_cvt<<<dim3(22, 16, 1), 256, 0, stream>>>(sw1, ew1T + (size_t)8 * HIDDEN * 1024,
      1024, HIDDEN, 1024, 0, 0);
  transpose_cvt<<<dim3(22, 16, 1), 256, 0, stream>>>(sw3, ew3T + (size_t)8 * HIDDEN * 1024,
      1024, HIDDEN, 1024, 0, 0);
  transpose_cvt<<<dim3(16, 22, 1), 256, 0, stream>>>(sw2, ew2T + (size_t)8 * 1024 * HIDP,
      HIDDEN, 1024, HIDP, 0, 0);

  // ---- attention path
  rmsnorm_kernel<<<TTOK, 256, 0, stream>>>(x, attnw, xn);
  gemm_bt<4><<<8 * 4 * 12, 256, 0, stream>>>(
      xn, wqkvT, TTOK, 1536, 1024, 1024, 1024, 4, nullptr, 0, nullptr, ropeAux);
  vt_kernel<<<dim3(32, 8), 256, 0, stream>>>(vb, vt);
  attn_kernel<<<dim3(16, NHEAD, 2), 256, 0, stream>>>(qb, kb, vt, ao);
  gemm_bt<2><<<8 * 4 * 8, 256, 0, stream>>>(
      ao, woT, TTOK, 1024, 1024, 1024, 1024, 4, hbuf, 1024, x, nil);

  // ---- MoE routing
  rmsnorm_router_kernel<<<TTOK, 256, 0, stream>>>(hbuf, moew, rw, hn, probs, tIdx, tW);
  hipMemsetAsync(slotOf, 0xFF, (size_t)TTOK * 2 * 4, stream);
  assign_kernel<<<9, 256, 0, stream>>>(tIdx, tW, tokList, gateW, neCnt, cntFull, slotOf);
  aux_kernel<<<1, 256, 0, stream>>>(probs, cntFull, auxp);

  // ---- experts (8 routed + shared as expert 8), unified dispatches
  gemm_dual9<<<8 * XBT * 22, 256, 0, stream>>>(hn, ew1T, ew3T, mact, tokList, neCnt);
  gemm_down9<<<8 * XBT * 16, 256, 0, stream>>>(mact, ew2T, eo, gateW, neCnt);
  combine_kernel<<<TTOK, 256, 0, stream>>>(outp, hbuf, eo, slotOf);
}